// Round 12
// baseline (708.063 us; speedup 1.0000x reference)
//
#include <hip/hip_runtime.h>
#include <stdint.h>
#include <stddef.h>

// ---------------------------------------------------------------------------
// B=8, D=512, H=8, HD=64, NS=8192, NT=4096
// R11: GEMM frozen at R7 structure. Changes:
//  - gemm_proj: G1+G2+G3b in one launch (1024 blocks, runtime epi branch)
//  - kv_partial: 8-way K-split (512 blocks, 2 blocks/CU), KVp/Ksp live in
//    msg1's dead region (kv chain runs before attn writes msg1)
// 11 launches total.
// ---------------------------------------------------------------------------

using ushort_t = unsigned short;
using short8 = __attribute__((ext_vector_type(8))) short;
using f32x4  = __attribute__((ext_vector_type(4))) float;

#define DEVI __device__ __forceinline__

DEVI float b2f(unsigned short u) {
    unsigned v = ((unsigned)u) << 16;
    return __builtin_bit_cast(float, v);
}
DEVI unsigned short f2b(float x) {
    unsigned u = __builtin_bit_cast(unsigned, x);
    u += 0x7FFFu + ((u >> 16) & 1u);   // RNE
    return (unsigned short)(u >> 16);
}
DEVI void gload16(const void* g, void* l) {
    __builtin_amdgcn_global_load_lds(
        (const __attribute__((address_space(1))) unsigned*)g,
        (__attribute__((address_space(3))) unsigned*)l, 16, 0, 0);
}

// ---------------------------------------------------------------------------
// GEMM (frozen R7): C[m][n] = epi( sum_k A[m][k] * Wt[n][k] )
// BM=BN=256, BK=64, 8 waves (2Mx4N), 2 LDS buffers (128KB), reg-pipelined.
// EPI: 0=none 1=elu+1 2=+bias[n]+addm[m][n] 3=relu
// ---------------------------------------------------------------------------
template <int EPI>
__global__ __launch_bounds__(512, 2)
void gemm_bf16(const ushort_t* __restrict__ A0, const ushort_t* __restrict__ A1,
               const ushort_t* __restrict__ Wt, ushort_t* __restrict__ C,
               const float* __restrict__ bias, const ushort_t* __restrict__ addm,
               int N, int K, int K0, int lda0, int lda1, int nn)
{
    __shared__ ushort_t As[2][256 * 64];   // 64KB
    __shared__ ushort_t Bs[2][256 * 64];   // 64KB
    const int tid = threadIdx.x;
    const int cpx = gridDim.x >> 3;
    const int lid = (blockIdx.x & 7) * cpx + (blockIdx.x >> 3);
    const int m0 = (lid / nn) * 256;
    const int n0 = (lid % nn) * 256;
    const int w = tid >> 6, l = tid & 63;
    const int wm = (w >> 2) * 128;
    const int wn = (w & 3) * 64;
    const int lr = l & 15, lg = l >> 4;
    const int srow = tid >> 3;
    const int sck  = (tid & 7) ^ (srow & 7);
    const int nk = K / 64;

    f32x4 accA[4][4] = {};
    f32x4 accB[4][4] = {};

    auto stageA = [&](int kt, int buf) {
        const int kb = kt * 64;
        const ushort_t* p; int ld;
        if (kb < K0) { p = A0 + (size_t)m0 * lda0 + kb; ld = lda0; }
        else         { p = A1 + (size_t)m0 * lda1 + (kb - K0); ld = lda1; }
        p += (size_t)srow * ld + sck * 8;
#pragma unroll
        for (int j = 0; j < 4; j++)
            gload16(p + (size_t)(j * 64) * ld,
                    (void*)(&As[buf][j * 4096] + tid * 8));
    };
    auto stageB = [&](int kt, int buf) {
        const ushort_t* p = Wt + (size_t)(n0 + srow) * K + kt * 64 + sck * 8;
#pragma unroll
        for (int j = 0; j < 4; j++)
            gload16(p + (size_t)(j * 64) * K,
                    (void*)(&Bs[buf][j * 4096] + tid * 8));
    };

    short8 aP[4], aQ[4], aR[4], b0[4], b1[4];

    auto ldA = [&](short8 (&dst)[4], int mh, int ks, int cb) {
#pragma unroll
        for (int mf = 0; mf < 4; mf++) {
            const int r = wm + mh * 64 + mf * 16 + lr;
            dst[mf] = *(const short8*)&As[cb][r * 64 + ((ks * 4 + lg) ^ (r & 7)) * 8];
        }
    };
    auto ldB = [&](short8 (&dst)[4], int ks, int cb) {
#pragma unroll
        for (int nf = 0; nf < 4; nf++) {
            const int r = wn + nf * 16 + lr;
            dst[nf] = *(const short8*)&Bs[cb][r * 64 + ((ks * 4 + lg) ^ (r & 7)) * 8];
        }
    };
    auto MM = [&](f32x4 (&ac)[4][4], short8 (&af)[4], short8 (&bf)[4]) {
        __builtin_amdgcn_s_setprio(1);
#pragma unroll
        for (int mf = 0; mf < 4; mf++)
#pragma unroll
            for (int nf = 0; nf < 4; nf++)
                ac[mf][nf] = __builtin_amdgcn_mfma_f32_16x16x32_bf16(
                    af[mf], bf[nf], ac[mf][nf], 0, 0, 0);
        __builtin_amdgcn_s_setprio(0);
    };

    stageA(0, 0); stageB(0, 0);
    asm volatile("s_waitcnt vmcnt(0)" ::: "memory");
    __builtin_amdgcn_s_barrier();
    ldA(aP, 0, 0, 0); ldB(b0, 0, 0);

    for (int t = 0; t < nk; ++t) {
        const int cur = t & 1;
        const bool pre = (t + 1) < nk;
        ldA(aQ, 1, 0, cur); ldB(b1, 1, cur);
        if (pre) stageA(t + 1, cur ^ 1);
        MM(accA, aP, b0);
        ldA(aR, 0, 1, cur);
        if (pre) stageB(t + 1, cur ^ 1);
        MM(accB, aQ, b0);
        ldA(aP, 1, 1, cur);
        MM(accA, aR, b1);
        MM(accB, aP, b1);
        if (pre) {
            asm volatile("s_waitcnt vmcnt(0)" ::: "memory");
            __builtin_amdgcn_s_barrier();
            ldA(aP, 0, 0, cur ^ 1); ldB(b0, 0, cur ^ 1);
        }
    }

#pragma unroll
    for (int mf = 0; mf < 4; mf++) {
#pragma unroll
        for (int i = 0; i < 4; i++) {
            const int mA = m0 + wm + mf * 16 + lg * 4 + i;
            const int mB = mA + 64;
#pragma unroll
            for (int nf = 0; nf < 4; nf++) {
                const int n = n0 + wn + nf * 16 + lr;
                float x = accA[mf][nf][i];
                float y = accB[mf][nf][i];
                if constexpr (EPI == 1) {
                    x = x > 0.f ? x + 1.f : __expf(x);
                    y = y > 0.f ? y + 1.f : __expf(y);
                }
                if constexpr (EPI == 2) {
                    x += bias[n] + b2f(addm[(size_t)mA * N + n]);
                    y += bias[n] + b2f(addm[(size_t)mB * N + n]);
                }
                if constexpr (EPI == 3) { x = fmaxf(x, 0.f); y = fmaxf(y, 0.f); }
                C[(size_t)mA * N + n] = f2b(x);
                C[(size_t)mB * N + n] = f2b(y);
            }
        }
    }
}

// ---------------------------------------------------------------------------
// gemm_proj: G1 (Qp=elu(sfT@wq)+1, [0,512)) + G2 (Kp=elu(tfT@wk)+1,
// [512,768)) + G3b (tfpos=P1@pw2+b2+tfT, [768,1024)) in ONE launch.
// K=512, lda=512, nn=2 for all three. Runtime epilogue branch (uniform).
// ---------------------------------------------------------------------------
__global__ __launch_bounds__(512, 2)
void gemm_proj(const ushort_t* __restrict__ sfT, const ushort_t* __restrict__ tfT,
               const ushort_t* __restrict__ P1,
               const ushort_t* __restrict__ wqT, const ushort_t* __restrict__ wkT,
               const ushort_t* __restrict__ pw2T,
               ushort_t* __restrict__ Qp, ushort_t* __restrict__ Kp,
               ushort_t* __restrict__ tfpos, const float* __restrict__ pos_b2)
{
    __shared__ ushort_t As[2][256 * 64];
    __shared__ ushort_t Bs[2][256 * 64];
    const int tid = threadIdx.x;
    const int cpx = gridDim.x >> 3;
    const int lid = (blockIdx.x & 7) * cpx + (blockIdx.x >> 3);
    const ushort_t* A0; const ushort_t* Wt; ushort_t* C; int loc; bool doElu;
    if (lid < 512)      { loc = lid;       A0 = sfT; Wt = wqT;  C = Qp;    doElu = true; }
    else if (lid < 768) { loc = lid - 512; A0 = tfT; Wt = wkT;  C = Kp;    doElu = true; }
    else                { loc = lid - 768; A0 = P1;  Wt = pw2T; C = tfpos; doElu = false; }
    const int m0 = (loc >> 1) * 256;
    const int n0 = (loc & 1) * 256;
    const int w = tid >> 6, l = tid & 63;
    const int wm = (w >> 2) * 128;
    const int wn = (w & 3) * 64;
    const int lr = l & 15, lg = l >> 4;
    const int srow = tid >> 3;
    const int sck  = (tid & 7) ^ (srow & 7);
    const int nk = 8;   // K=512

    f32x4 accA[4][4] = {};
    f32x4 accB[4][4] = {};

    auto stageA = [&](int kt, int buf) {
        const ushort_t* p = A0 + (size_t)(m0 + srow) * 512 + kt * 64 + sck * 8;
#pragma unroll
        for (int j = 0; j < 4; j++)
            gload16(p + (size_t)(j * 64) * 512,
                    (void*)(&As[buf][j * 4096] + tid * 8));
    };
    auto stageB = [&](int kt, int buf) {
        const ushort_t* p = Wt + (size_t)(n0 + srow) * 512 + kt * 64 + sck * 8;
#pragma unroll
        for (int j = 0; j < 4; j++)
            gload16(p + (size_t)(j * 64) * 512,
                    (void*)(&Bs[buf][j * 4096] + tid * 8));
    };

    short8 aP[4], aQ[4], aR[4], b0[4], b1[4];

    auto ldA = [&](short8 (&dst)[4], int mh, int ks, int cb) {
#pragma unroll
        for (int mf = 0; mf < 4; mf++) {
            const int r = wm + mh * 64 + mf * 16 + lr;
            dst[mf] = *(const short8*)&As[cb][r * 64 + ((ks * 4 + lg) ^ (r & 7)) * 8];
        }
    };
    auto ldB = [&](short8 (&dst)[4], int ks, int cb) {
#pragma unroll
        for (int nf = 0; nf < 4; nf++) {
            const int r = wn + nf * 16 + lr;
            dst[nf] = *(const short8*)&Bs[cb][r * 64 + ((ks * 4 + lg) ^ (r & 7)) * 8];
        }
    };
    auto MM = [&](f32x4 (&ac)[4][4], short8 (&af)[4], short8 (&bf)[4]) {
        __builtin_amdgcn_s_setprio(1);
#pragma unroll
        for (int mf = 0; mf < 4; mf++)
#pragma unroll
            for (int nf = 0; nf < 4; nf++)
                ac[mf][nf] = __builtin_amdgcn_mfma_f32_16x16x32_bf16(
                    af[mf], bf[nf], ac[mf][nf], 0, 0, 0);
        __builtin_amdgcn_s_setprio(0);
    };

    stageA(0, 0); stageB(0, 0);
    asm volatile("s_waitcnt vmcnt(0)" ::: "memory");
    __builtin_amdgcn_s_barrier();
    ldA(aP, 0, 0, 0); ldB(b0, 0, 0);

    for (int t = 0; t < nk; ++t) {
        const int cur = t & 1;
        const bool pre = (t + 1) < nk;
        ldA(aQ, 1, 0, cur); ldB(b1, 1, cur);
        if (pre) stageA(t + 1, cur ^ 1);
        MM(accA, aP, b0);
        ldA(aR, 0, 1, cur);
        if (pre) stageB(t + 1, cur ^ 1);
        MM(accB, aQ, b0);
        ldA(aP, 1, 1, cur);
        MM(accA, aR, b1);
        MM(accB, aP, b1);
        if (pre) {
            asm volatile("s_waitcnt vmcnt(0)" ::: "memory");
            __builtin_amdgcn_s_barrier();
            ldA(aP, 0, 0, cur ^ 1); ldB(b0, 0, cur ^ 1);
        }
    }

#pragma unroll
    for (int mf = 0; mf < 4; mf++) {
#pragma unroll
        for (int i = 0; i < 4; i++) {
            const int mA = m0 + wm + mf * 16 + lg * 4 + i;
            const int mB = mA + 64;
#pragma unroll
            for (int nf = 0; nf < 4; nf++) {
                const int n = n0 + wn + nf * 16 + lr;
                float x = accA[mf][nf][i];
                float y = accB[mf][nf][i];
                if (doElu) {
                    x = x > 0.f ? x + 1.f : __expf(x);
                    y = y > 0.f ? y + 1.f : __expf(y);
                } else {
                    x += pos_b2[n] + b2f(tfT[(size_t)mA * 512 + n]);
                    y += pos_b2[n] + b2f(tfT[(size_t)mB * 512 + n]);
                }
                C[(size_t)mA * 512 + n] = f2b(x);
                C[(size_t)mB * 512 + n] = f2b(y);
            }
        }
    }
}

// ---------------------------------------------------------------------------
// prep: ALL transposes + pos MLP in one launch (ranges as in R10).
// ---------------------------------------------------------------------------
__global__ __launch_bounds__(256)
void prep(const float* __restrict__ sfeat, const float* __restrict__ tfeat,
          const float* __restrict__ xyz, const float* __restrict__ pw1,
          const float* __restrict__ pb1,
          const float* wq, const float* wk, const float* wv, const float* wm,
          const float* pw2, const float* w1, const float* w2,
          ushort_t* sfT, ushort_t* tfT, ushort_t* P1,
          ushort_t* wqT, ushort_t* wkT, ushort_t* wvT, ushort_t* wmT,
          ushort_t* pw2T, ushort_t* w1T, ushort_t* w2T)
{
    const int bid = blockIdx.x;
    const int t = threadIdx.x;
    if (bid >= 12992) {   // pos MLP: 4 rows per block
        const int m = (bid - 12992) * 4 + (t >> 6);
        const int n0 = (t & 63) * 8;
        const float x = xyz[m * 3 + 0], y = xyz[m * 3 + 1], z = xyz[m * 3 + 2];
        short8 o;
#pragma unroll
        for (int j = 0; j < 8; j++) {
            const int n = n0 + j;
            float v = x * pw1[n] + y * pw1[512 + n] + z * pw1[1024 + n] + pb1[n];
            o[j] = (short)f2b(fmaxf(v, 0.f));
        }
        *(short8*)&P1[(size_t)m * 512 + n0] = o;
        return;
    }
    __shared__ float tile[64][65];
    const float* src; ushort_t* dst; int R, Cc, c0, r0;
    if (bid < 8192) {
        const int b = bid >> 10, rem = bid & 1023;
        src = sfeat + (size_t)b * 512 * 8192; dst = sfT + (size_t)b * 512 * 8192;
        R = 512; Cc = 8192; c0 = (rem & 127) * 64; r0 = (rem >> 7) * 64;
    } else if (bid < 12288) {
        const int lcl = bid - 8192; const int b = lcl >> 9, rem = lcl & 511;
        src = tfeat + (size_t)b * 512 * 4096; dst = tfT + (size_t)b * 512 * 4096;
        R = 512; Cc = 4096; c0 = (rem & 63) * 64; r0 = (rem >> 6) * 64;
    } else {
        const int lcl = bid - 12288;
        if (lcl < 320) {
            const int wsel = lcl >> 6, local = lcl & 63;
            const float* srcs[5] = {wq, wk, wv, wm, pw2};
            ushort_t* dsts[5] = {wqT, wkT, wvT, wmT, pw2T};
            src = srcs[wsel]; dst = dsts[wsel];
            R = 512; Cc = 512; c0 = (local & 7) * 64; r0 = (local >> 3) * 64;
        } else if (lcl < 576) {
            const int local = lcl - 320;
            src = w1; dst = w1T; R = 1024; Cc = 1024;
            c0 = (local & 15) * 64; r0 = (local >> 4) * 64;
        } else {
            const int local = lcl - 576;
            src = w2; dst = w2T; R = 1024; Cc = 512;
            c0 = (local & 7) * 64; r0 = (local >> 3) * 64;
        }
    }
#pragma unroll
    for (int i = 0; i < 4; i++) {
        const int r = (t >> 4) + i * 16;
        const int c = (t & 15) * 4;
        const float4 v = *(const float4*)&src[(size_t)(r0 + r) * Cc + c0 + c];
        tile[r][c + 0] = v.x; tile[r][c + 1] = v.y;
        tile[r][c + 2] = v.z; tile[r][c + 3] = v.w;
    }
    __syncthreads();
#pragma unroll
    for (int i = 0; i < 2; i++) {
        const int c = (t >> 3) + i * 32;
        const int rs = (t & 7) * 8;
        short8 o;
#pragma unroll
        for (int j = 0; j < 8; j++) o[j] = (short)f2b(tile[rs + j][c]);
        *(short8*)&dst[(size_t)(c0 + c) * R + r0 + rs] = o;
    }
}

// ---------------------------------------------------------------------------
// KV partials: grid (8 ksplit, 8 h, 8 b) = 512 blocks, 2/CU.
// KVp[sp][bh][d][e] (f32), Ksp[sp][bh][d] (f32)
// ---------------------------------------------------------------------------
__global__ __launch_bounds__(256)
void kv_partial(const ushort_t* __restrict__ Kp, const ushort_t* __restrict__ V,
                float* __restrict__ KVp, float* __restrict__ Ksp)
{
    __shared__ ushort_t Ks[256 * 64];
    __shared__ ushort_t Vs[256 * 64];
    const int t = threadIdx.x;
    const int sp = blockIdx.x, h = blockIdx.y, b = blockIdx.z;
    const int d0 = t >> 2, e0 = (t & 3) * 16;
    const int srow = t >> 3, scol = (t & 7) * 8;
    float acc[16] = {};
    float ksum = 0.f;
    for (int c = 0; c < 2; c++) {
        if (c) __syncthreads();
        const size_t sbase = (size_t)b * 4096 + sp * 512 + c * 256;
#pragma unroll
        for (int i = 0; i < 8; i++) {
            const size_t go = (sbase + i * 32 + srow) * 512 + h * 64 + scol;
            gload16(Kp + go, (void*)(&Ks[i * 2048] + t * 8));
            gload16(V + go, (void*)(&Vs[i * 2048] + t * 8));
        }
        __syncthreads();
        for (int s = 0; s < 256; s++) {
            const float k = b2f(Ks[s * 64 + d0]);
            if ((t & 3) == 0) ksum += k;
            const short8 v0 = *(const short8*)&Vs[s * 64 + e0];
            const short8 v1 = *(const short8*)&Vs[s * 64 + e0 + 8];
#pragma unroll
            for (int j = 0; j < 8; j++) {
                acc[j]     += k * b2f((unsigned short)v0[j]);
                acc[8 + j] += k * b2f((unsigned short)v1[j]);
            }
        }
    }
    const int bh = b * 8 + h;
    float* kvo = KVp + (((size_t)sp * 64 + bh) * 64 + d0) * 64 + e0;
#pragma unroll
    for (int j = 0; j < 16; j++) kvo[j] = acc[j];
    if ((t & 3) == 0) Ksp[((size_t)sp * 64 + bh) * 64 + d0] = ksum;
}

// KVt[bh][80][64]: rows 0-63 = KV[e][d], row 64 = Ksum[d], rows 65-79 = 0
__global__ __launch_bounds__(256)
void kv_finalize(const float* __restrict__ KVp, const float* __restrict__ Ksp,
                 ushort_t* __restrict__ KVt)
{
    const int bh = blockIdx.x, t = threadIdx.x;
    ushort_t* o = KVt + (size_t)bh * 5120;
#pragma unroll
    for (int i = 0; i < 16; i++) {
        const int idx = i * 256 + t;
        const int e = idx >> 6, d = idx & 63;
        float s = 0.f;
#pragma unroll
        for (int sp = 0; sp < 8; sp++)
            s += KVp[(((size_t)sp * 64 + bh) * 64 + d) * 64 + e];
        o[idx] = f2b(s);
    }
    if (t < 64) {
        float s = 0.f;
#pragma unroll
        for (int sp = 0; sp < 8; sp++) s += Ksp[((size_t)sp * 64 + bh) * 64 + t];
        o[4096 + t] = f2b(s);
    }
    for (int idx = 4160 + t; idx < 5120; idx += 256) o[idx] = 0;
}

// msg1[row][h*64+e] = (Qp[row] @ KV) * 1/(Qp[row].Ksum + eps)
__global__ __launch_bounds__(256, 2)
void attn_apply(const ushort_t* __restrict__ Qp, const ushort_t* __restrict__ KVt,
                ushort_t* __restrict__ msg1)
{
    __shared__ ushort_t As[256 * 64];
    __shared__ ushort_t Bs[80 * 64];
    const int t = threadIdx.x;
    const int ch = blockIdx.x, h = blockIdx.y, b = blockIdx.z;
    const int w = t >> 6, l = t & 63;
    const int lr = l & 15, lg = l >> 4;
    const int row0 = ch * 256;
    const int srow = t >> 3;
    const int sc = ((t & 7) ^ (srow & 7)) * 8;
    const ushort_t* kv = KVt + (size_t)(b * 8 + h) * 5120;
#pragma unroll
    for (int i = 0; i < 2; i++)
        gload16(kv + (size_t)(i * 32 + srow) * 64 + sc,
                (void*)(&Bs[i * 2048] + t * 8));
    if (t < 128)
        gload16(kv + (size_t)(64 + srow) * 64 + sc,
                (void*)(&Bs[4096] + t * 8));
    const ushort_t* qb = Qp + ((size_t)b * 8192 + row0) * 512 + h * 64;
#pragma unroll
    for (int i = 0; i < 8; i++)
        gload16(qb + (size_t)(i * 32 + srow) * 512 + sc,
                (void*)(&As[i * 2048] + t * 8));
    __syncthreads();
    f32x4 acc[4][5] = {};
    const int wr = w * 64;
#pragma unroll
    for (int ks = 0; ks < 2; ks++) {
        const int kswz = ((ks * 4 + lg) ^ (lr & 7)) * 8;
        short8 a[4], bb[5];
#pragma unroll
        for (int mf = 0; mf < 4; mf++)
            a[mf] = *(const short8*)&As[(wr + mf * 16 + lr) * 64 + kswz];
#pragma unroll
        for (int nf = 0; nf < 5; nf++)
            bb[nf] = *(const short8*)&Bs[(nf * 16 + lr) * 64 + kswz];
#pragma unroll
        for (int mf = 0; mf < 4; mf++)
#pragma unroll
            for (int nf = 0; nf < 5; nf++)
                acc[mf][nf] = __builtin_amdgcn_mfma_f32_16x16x32_bf16(
                    a[mf], bb[nf], acc[mf][nf], 0, 0, 0);
    }
#pragma unroll
    for (int mf = 0; mf < 4; mf++) {
#pragma unroll
        for (int i = 0; i < 4; i++) {
            const int m = row0 + wr + mf * 16 + lg * 4 + i;
            const float zden = __shfl(acc[mf][4][i], (l & 48));
            const float z = 1.f / (zden + 1e-6f);
#pragma unroll
            for (int nf = 0; nf < 4; nf++) {
                const int e = nf * 16 + lr;
                msg1[((size_t)b * 8192 + m) * 512 + h * 64 + e] =
                    f2b(acc[mf][nf][i] * z);
            }
        }
    }
}

// in-place LayerNorm over rows of 512 bf16; one wave per row (LN1)
__global__ __launch_bounds__(256)
void layer_norm_k(ushort_t* __restrict__ X, const float* __restrict__ g,
                  const float* __restrict__ bta)
{
    const int t = threadIdx.x;
    const int row = blockIdx.x * 4 + (t >> 6);
    const int l = t & 63;
    ushort_t* x = X + (size_t)row * 512;
    const short8 v = *(const short8*)&x[l * 8];
    float f[8];
    float s = 0.f;
#pragma unroll
    for (int j = 0; j < 8; j++) { f[j] = b2f((unsigned short)v[j]); s += f[j]; }
#pragma unroll
    for (int o = 32; o > 0; o >>= 1) s += __shfl_xor(s, o);
    const float mean = s * (1.f / 512.f);
    float vs = 0.f;
#pragma unroll
    for (int j = 0; j < 8; j++) { const float d = f[j] - mean; vs += d * d; }
#pragma unroll
    for (int o = 32; o > 0; o >>= 1) vs += __shfl_xor(vs, o);
    const float rstd = rsqrtf(vs * (1.f / 512.f) + 1e-5f);
    short8 ov;
#pragma unroll
    for (int j = 0; j < 8; j++) {
        const int c = l * 8 + j;
        ov[j] = (short)f2b((f[j] - mean) * rstd * g[c] + bta[c]);
    }
    *(short8*)&x[l * 8] = ov;
}

// Fused LN2 + residual + transpose
__global__ __launch_bounds__(256)
void ln2_final(const ushort_t* __restrict__ outp, const ushort_t* __restrict__ sfT,
               const float* __restrict__ g, const float* __restrict__ bta,
               float* __restrict__ out)
{
    __shared__ ushort_t tile[64][514];
    const int t = threadIdx.x;
    const int ns0 = blockIdx.x * 64, b = blockIdx.y;
    const int w = t >> 6, l = t & 63;
#pragma unroll
    for (int rr = 0; rr < 16; rr++) {
        const int r = w * 16 + rr;
        const size_t grow = (size_t)b * 8192 + ns0 + r;
        const short8 v = *(const short8*)&outp[grow * 512 + l * 8];
        float f[8];
        float s = 0.f;
#pragma unroll
        for (int j = 0; j < 8; j++) { f[j] = b2f((unsigned short)v[j]); s += f[j]; }
#pragma unroll
        for (int o = 32; o > 0; o >>= 1) s += __shfl_xor(s, o);
        const float mean = s * (1.f / 512.f);
        float vs = 0.f;
#pragma unroll
        for (int j = 0; j < 8; j++) { const float d = f[j] - mean; vs += d * d; }
#pragma unroll
        for (int o = 32; o > 0; o >>= 1) vs += __shfl_xor(vs, o);
        const float rstd = rsqrtf(vs * (1.f / 512.f) + 1e-5f);
        const short8 sv = *(const short8*)&sfT[grow * 512 + l * 8];
        short8 ov;
#pragma unroll
        for (int j = 0; j < 8; j++) {
            const int c = l * 8 + j;
            ov[j] = (short)f2b(b2f((unsigned short)sv[j]) +
                               (f[j] - mean) * rstd * g[c] + bta[c]);
        }
        *(short8*)&tile[r][l * 8] = ov;
    }
    __syncthreads();
#pragma unroll
    for (int i = 0; i < 32; i++) {
        const int d = (t >> 4) + i * 16;
        const int nss = (t & 15) * 4;
        float4 o;
        o.x = b2f(tile[nss + 0][d]);
        o.y = b2f(tile[nss + 1][d]);
        o.z = b2f(tile[nss + 2][d]);
        o.w = b2f(tile[nss + 3][d]);
        *(float4*)&out[((size_t)b * 512 + d) * 8192 + ns0 + nss] = o;
    }
}

// ---------------------------------------------------------------------------
extern "C" void kernel_launch(void* const* d_in, const int* in_sizes, int n_in,
                              void* d_out, int out_size, void* d_ws, size_t ws_size,
                              hipStream_t stream)
{
    (void)in_sizes; (void)n_in; (void)out_size; (void)ws_size;
    const float* search_feat   = (const float*)d_in[0];
    const float* template_feat = (const float*)d_in[2];
    const float* template_xyz  = (const float*)d_in[3];
    const float* pos_w1  = (const float*)d_in[4];
    const float* pos_b1  = (const float*)d_in[5];
    const float* pos_w2  = (const float*)d_in[6];
    const float* pos_b2  = (const float*)d_in[7];
    const float* wq      = (const float*)d_in[8];
    const float* wk      = (const float*)d_in[9];
    const float* wv      = (const float*)d_in[10];
    const float* w_merge = (const float*)d_in[11];
    const float* mlp_w1  = (const float*)d_in[12];
    const float* mlp_w2  = (const float*)d_in[13];
    const float* ln1_g   = (const float*)d_in[14];
    const float* ln1_b   = (const float*)d_in[15];
    const float* ln2_g   = (const float*)d_in[16];
    const float* ln2_b   = (const float*)d_in[17];
    float* out = (float*)d_out;

    char* ws = (char*)d_ws;
    ushort_t* sfT    = (ushort_t*)(ws + 0);           // [65536][512]
    ushort_t* Qp     = (ushort_t*)(ws + 67108864);    // [65536][512]; reused as outp
    ushort_t* tfT    = (ushort_t*)(ws + 134217728);   // [32768][512]
    ushort_t* Kp     = (ushort_t*)(ws + 167772160);   // [32768][512]
    ushort_t* msg2   = (ushort_t*)(ws + 134217728);   // [65536][512], overlaps tfT+Kp
    ushort_t* P1     = (ushort_t*)(ws + 201326592);   // [32768][512]
    ushort_t* Vv     = (ushort_t*)(ws + 201326592);   // reuses P1 slot
    ushort_t* tfpos  = (ushort_t*)(ws + 234881024);   // [32768][512]
    ushort_t* msg1   = (ushort_t*)(ws + 268435456);   // [65536][512]
    ushort_t* hidden = (ushort_t*)(ws + 201326592);   // [65536][1024]
    ushort_t* outp   = Qp;
    ushort_t* wqT  = (ushort_t*)(ws + 335544320);
    ushort_t* wkT  = (ushort_t*)(ws + 336068608);
    ushort_t* wvT  = (ushort_t*)(ws + 336592896);
    ushort_t* wmT  = (ushort_t*)(ws + 337117184);
    ushort_t* pw2T = (ushort_t*)(ws + 337641472);
    ushort_t* w1T  = (ushort_t*)(ws + 338165760);
    ushort_t* w2T  = (ushort_t*)(ws + 340262912);
    // KVp/Ksp live in msg1's region (dead until attn_apply writes msg1)
    float*    KVp  = (float*)(ws + 268435456);        // 8*64*64*64*4 = 8.4MB
    float*    Ksp  = (float*)(ws + 276824064);        // 8*64*64*4 = 131KB
    ushort_t* KVt  = (ushort_t*)(ws + 345571328);     // [64][80][64]

    // 1: all transposes + pos MLP
    prep<<<dim3(21184), 256, 0, stream>>>(
        search_feat, template_feat, template_xyz, pos_w1, pos_b1,
        wq, wk, wv, w_merge, pos_w2, mlp_w1, mlp_w2,
        sfT, tfT, P1, wqT, wkT, wvT, wmT, pw2T, w1T, w2T);
    // 2: G1 + G2 + G3b
    gemm_proj<<<dim3(1024), 512, 0, stream>>>(sfT, tfT, P1, wqT, wkT, pw2T,
                                              Qp, Kp, tfpos, pos_b2);
    // 3: G4 (V projection)
    gemm_bf16<0><<<dim3(256), 512, 0, stream>>>(tfpos, nullptr, wvT, Vv,
                                                nullptr, nullptr, 512, 512, 512, 512, 0, 2);
    // 4-6: linear attention core
    kv_partial<<<dim3(8, 8, 8), 256, 0, stream>>>(Kp, Vv, KVp, Ksp);
    kv_finalize<<<dim3(64), 256, 0, stream>>>(KVp, Ksp, KVt);
    attn_apply<<<dim3(32, 8, 8), 256, 0, stream>>>(Qp, KVt, msg1);
    // 7-8: merge + LN1
    gemm_bf16<0><<<dim3(512), 512, 0, stream>>>(msg1, nullptr, wmT, msg2,
                                                nullptr, nullptr, 512, 512, 512, 512, 0, 2);
    layer_norm_k<<<dim3(16384), 256, 0, stream>>>(msg2, ln1_g, ln1_b);
    // 9-10: MLP
    gemm_bf16<3><<<dim3(1024), 512, 0, stream>>>(sfT, msg2, w1T, hidden,
                                                 nullptr, nullptr, 1024, 1024, 512, 512, 512, 4);
    gemm_bf16<0><<<dim3(512), 512, 0, stream>>>(hidden, nullptr, w2T, outp,
                                                nullptr, nullptr, 512, 1024, 1024, 1024, 0, 2);
    // 11: fused LN2 + residual + transpose
    ln2_final<<<dim3(128, 8), 256, 0, stream>>>(outp, sfT, ln2_g, ln2_b, out);
}

// Round 13
// 658.477 us; speedup vs baseline: 1.0753x; 1.0753x over previous
//
#include <hip/hip_runtime.h>
#include <stdint.h>
#include <stddef.h>

// ---------------------------------------------------------------------------
// B=8, D=512, H=8, HD=64, NS=8192, NT=4096
// R12: ALL GEMMs swapped to the m97-proven structure: 128x128 tile, BK=64,
// SINGLE 32KB LDS buffer, 4 waves (2Mx2N), plain 2-barrier loop. Pipelining
// comes from 4-5 co-resident blocks/CU (cross-block overlap, m114), which the
// 1-resident 256x256 structure could never get. Chunk-XOR swizzle unchanged.
// prep / proj-merge / kv 8-split / attn / LN kernels unchanged from R11.
// ---------------------------------------------------------------------------

using ushort_t = unsigned short;
using short8 = __attribute__((ext_vector_type(8))) short;
using f32x4  = __attribute__((ext_vector_type(4))) float;

#define DEVI __device__ __forceinline__

DEVI float b2f(unsigned short u) {
    unsigned v = ((unsigned)u) << 16;
    return __builtin_bit_cast(float, v);
}
DEVI unsigned short f2b(float x) {
    unsigned u = __builtin_bit_cast(unsigned, x);
    u += 0x7FFFu + ((u >> 16) & 1u);   // RNE
    return (unsigned short)(u >> 16);
}
DEVI void gload16(const void* g, void* l) {
    __builtin_amdgcn_global_load_lds(
        (const __attribute__((address_space(1))) unsigned*)g,
        (__attribute__((address_space(3))) unsigned*)l, 16, 0, 0);
}

// ---------------------------------------------------------------------------
// GEMM (m97 structure): C[m][n] = epi( sum_k A[m][k] * Wt[n][k] )
// 128x128 tile, BK=64, 256 threads (4 waves 2Mx2N), single 32KB LDS buffer.
// Per K-tile: stage A+B (8 gload16/thread-group) -> vmcnt(0)+barrier ->
// 2 k-steps x {4+4 ds_read_b128, 16 MFMA} -> barrier. 4-5 blocks/CU.
// EPI: 0=none 1=elu+1 2=+bias[n]+addm[m][n] 3=relu
// ---------------------------------------------------------------------------
template <int EPI>
__global__ __launch_bounds__(256, 4)
void gemm128(const ushort_t* __restrict__ A0, const ushort_t* __restrict__ A1,
             const ushort_t* __restrict__ Wt, ushort_t* __restrict__ C,
             const float* __restrict__ bias, const ushort_t* __restrict__ addm,
             int N, int K, int K0, int lda0, int lda1, int nn)
{
    __shared__ ushort_t As[128 * 64];   // 16KB
    __shared__ ushort_t Bs[128 * 64];   // 16KB
    const int tid = threadIdx.x;
    const int cpx = gridDim.x >> 3;
    const int lid = (blockIdx.x & 7) * cpx + (blockIdx.x >> 3);
    const int m0 = (lid / nn) * 128;
    const int n0 = (lid % nn) * 128;
    const int w = tid >> 6, l = tid & 63;
    const int wm = (w >> 1) * 64, wn = (w & 1) * 64;
    const int lr = l & 15, lg = l >> 4;
    const int srow = tid >> 3;                 // 0..31
    const int sck  = (tid & 7) ^ (srow & 7);   // pre-swizzled k-chunk
    const int nk = K / 64;

    f32x4 acc[4][4] = {};

    for (int t = 0; t < nk; ++t) {
        const int kb = t * 64;
        {
            const ushort_t* p; int ld;
            if (kb < K0) { p = A0 + (size_t)m0 * lda0 + kb; ld = lda0; }
            else         { p = A1 + (size_t)m0 * lda1 + (kb - K0); ld = lda1; }
            p += (size_t)srow * ld + sck * 8;
#pragma unroll
            for (int j = 0; j < 4; j++)
                gload16(p + (size_t)(j * 32) * ld, (void*)(&As[j * 2048] + tid * 8));
            const ushort_t* q = Wt + (size_t)(n0 + srow) * K + kb + sck * 8;
#pragma unroll
            for (int j = 0; j < 4; j++)
                gload16(q + (size_t)(j * 32) * K, (void*)(&Bs[j * 2048] + tid * 8));
        }
        asm volatile("s_waitcnt vmcnt(0)" ::: "memory");
        __builtin_amdgcn_s_barrier();
#pragma unroll
        for (int ks = 0; ks < 2; ks++) {
            short8 a[4], b[4];
#pragma unroll
            for (int mf = 0; mf < 4; mf++) {
                const int r = wm + mf * 16 + lr;
                a[mf] = *(const short8*)&As[r * 64 + ((ks * 4 + lg) ^ (r & 7)) * 8];
            }
#pragma unroll
            for (int nf = 0; nf < 4; nf++) {
                const int r = wn + nf * 16 + lr;
                b[nf] = *(const short8*)&Bs[r * 64 + ((ks * 4 + lg) ^ (r & 7)) * 8];
            }
            __builtin_amdgcn_s_setprio(1);
#pragma unroll
            for (int mf = 0; mf < 4; mf++)
#pragma unroll
                for (int nf = 0; nf < 4; nf++)
                    acc[mf][nf] = __builtin_amdgcn_mfma_f32_16x16x32_bf16(
                        a[mf], b[nf], acc[mf][nf], 0, 0, 0);
            __builtin_amdgcn_s_setprio(0);
        }
        __builtin_amdgcn_s_barrier();
    }

#pragma unroll
    for (int mf = 0; mf < 4; mf++) {
#pragma unroll
        for (int i = 0; i < 4; i++) {
            const int m = m0 + wm + mf * 16 + lg * 4 + i;
#pragma unroll
            for (int nf = 0; nf < 4; nf++) {
                const int n = n0 + wn + nf * 16 + lr;
                float x = acc[mf][nf][i];
                if constexpr (EPI == 1) { x = x > 0.f ? x + 1.f : __expf(x); }
                if constexpr (EPI == 2) { x += bias[n] + b2f(addm[(size_t)m * N + n]); }
                if constexpr (EPI == 3) { x = fmaxf(x, 0.f); }
                C[(size_t)m * N + n] = f2b(x);
            }
        }
    }
}

// ---------------------------------------------------------------------------
// gemm_proj (m97 structure): G1 (Qp=elu(sfT@wq)+1, [0,2048)) +
// G2 (Kp=elu(tfT@wk)+1, [2048,3072)) + G3b (tfpos=P1@pw2+b2+tfT, [3072,4096)).
// K=512, lda=512, nn=4 for all three.
// ---------------------------------------------------------------------------
__global__ __launch_bounds__(256, 4)
void gemm_proj(const ushort_t* __restrict__ sfT, const ushort_t* __restrict__ tfT,
               const ushort_t* __restrict__ P1,
               const ushort_t* __restrict__ wqT, const ushort_t* __restrict__ wkT,
               const ushort_t* __restrict__ pw2T,
               ushort_t* __restrict__ Qp, ushort_t* __restrict__ Kp,
               ushort_t* __restrict__ tfpos, const float* __restrict__ pos_b2)
{
    __shared__ ushort_t As[128 * 64];
    __shared__ ushort_t Bs[128 * 64];
    const int tid = threadIdx.x;
    const int cpx = gridDim.x >> 3;
    const int lid = (blockIdx.x & 7) * cpx + (blockIdx.x >> 3);
    const ushort_t* A0; const ushort_t* Wt; ushort_t* C; int loc; bool doElu;
    if (lid < 2048)      { loc = lid;        A0 = sfT; Wt = wqT;  C = Qp;    doElu = true; }
    else if (lid < 3072) { loc = lid - 2048; A0 = tfT; Wt = wkT;  C = Kp;    doElu = true; }
    else                 { loc = lid - 3072; A0 = P1;  Wt = pw2T; C = tfpos; doElu = false; }
    const int m0 = (loc >> 2) * 128;
    const int n0 = (loc & 3) * 128;
    const int w = tid >> 6, l = tid & 63;
    const int wm = (w >> 1) * 64, wn = (w & 1) * 64;
    const int lr = l & 15, lg = l >> 4;
    const int srow = tid >> 3;
    const int sck  = (tid & 7) ^ (srow & 7);

    f32x4 acc[4][4] = {};

    for (int t = 0; t < 8; ++t) {
        const int kb = t * 64;
        {
            const ushort_t* p = A0 + (size_t)(m0 + srow) * 512 + kb + sck * 8;
#pragma unroll
            for (int j = 0; j < 4; j++)
                gload16(p + (size_t)(j * 32) * 512, (void*)(&As[j * 2048] + tid * 8));
            const ushort_t* q = Wt + (size_t)(n0 + srow) * 512 + kb + sck * 8;
#pragma unroll
            for (int j = 0; j < 4; j++)
                gload16(q + (size_t)(j * 32) * 512, (void*)(&Bs[j * 2048] + tid * 8));
        }
        asm volatile("s_waitcnt vmcnt(0)" ::: "memory");
        __builtin_amdgcn_s_barrier();
#pragma unroll
        for (int ks = 0; ks < 2; ks++) {
            short8 a[4], b[4];
#pragma unroll
            for (int mf = 0; mf < 4; mf++) {
                const int r = wm + mf * 16 + lr;
                a[mf] = *(const short8*)&As[r * 64 + ((ks * 4 + lg) ^ (r & 7)) * 8];
            }
#pragma unroll
            for (int nf = 0; nf < 4; nf++) {
                const int r = wn + nf * 16 + lr;
                b[nf] = *(const short8*)&Bs[r * 64 + ((ks * 4 + lg) ^ (r & 7)) * 8];
            }
            __builtin_amdgcn_s_setprio(1);
#pragma unroll
            for (int mf = 0; mf < 4; mf++)
#pragma unroll
                for (int nf = 0; nf < 4; nf++)
                    acc[mf][nf] = __builtin_amdgcn_mfma_f32_16x16x32_bf16(
                        a[mf], b[nf], acc[mf][nf], 0, 0, 0);
            __builtin_amdgcn_s_setprio(0);
        }
        __builtin_amdgcn_s_barrier();
    }

#pragma unroll
    for (int mf = 0; mf < 4; mf++) {
#pragma unroll
        for (int i = 0; i < 4; i++) {
            const int m = m0 + wm + mf * 16 + lg * 4 + i;
#pragma unroll
            for (int nf = 0; nf < 4; nf++) {
                const int n = n0 + wn + nf * 16 + lr;
                float x = acc[mf][nf][i];
                if (doElu) {
                    x = x > 0.f ? x + 1.f : __expf(x);
                } else {
                    x += pos_b2[n] + b2f(tfT[(size_t)m * 512 + n]);
                }
                C[(size_t)m * 512 + n] = f2b(x);
            }
        }
    }
}

// ---------------------------------------------------------------------------
// prep: ALL transposes + pos MLP in one launch (ranges as in R10/R11).
// ---------------------------------------------------------------------------
__global__ __launch_bounds__(256)
void prep(const float* __restrict__ sfeat, const float* __restrict__ tfeat,
          const float* __restrict__ xyz, const float* __restrict__ pw1,
          const float* __restrict__ pb1,
          const float* wq, const float* wk, const float* wv, const float* wm,
          const float* pw2, const float* w1, const float* w2,
          ushort_t* sfT, ushort_t* tfT, ushort_t* P1,
          ushort_t* wqT, ushort_t* wkT, ushort_t* wvT, ushort_t* wmT,
          ushort_t* pw2T, ushort_t* w1T, ushort_t* w2T)
{
    const int bid = blockIdx.x;
    const int t = threadIdx.x;
    if (bid >= 12992) {   // pos MLP: 4 rows per block
        const int m = (bid - 12992) * 4 + (t >> 6);
        const int n0 = (t & 63) * 8;
        const float x = xyz[m * 3 + 0], y = xyz[m * 3 + 1], z = xyz[m * 3 + 2];
        short8 o;
#pragma unroll
        for (int j = 0; j < 8; j++) {
            const int n = n0 + j;
            float v = x * pw1[n] + y * pw1[512 + n] + z * pw1[1024 + n] + pb1[n];
            o[j] = (short)f2b(fmaxf(v, 0.f));
        }
        *(short8*)&P1[(size_t)m * 512 + n0] = o;
        return;
    }
    __shared__ float tile[64][65];
    const float* src; ushort_t* dst; int R, Cc, c0, r0;
    if (bid < 8192) {
        const int b = bid >> 10, rem = bid & 1023;
        src = sfeat + (size_t)b * 512 * 8192; dst = sfT + (size_t)b * 512 * 8192;
        R = 512; Cc = 8192; c0 = (rem & 127) * 64; r0 = (rem >> 7) * 64;
    } else if (bid < 12288) {
        const int lcl = bid - 8192; const int b = lcl >> 9, rem = lcl & 511;
        src = tfeat + (size_t)b * 512 * 4096; dst = tfT + (size_t)b * 512 * 4096;
        R = 512; Cc = 4096; c0 = (rem & 63) * 64; r0 = (rem >> 6) * 64;
    } else {
        const int lcl = bid - 12288;
        if (lcl < 320) {
            const int wsel = lcl >> 6, local = lcl & 63;
            const float* srcs[5] = {wq, wk, wv, wm, pw2};
            ushort_t* dsts[5] = {wqT, wkT, wvT, wmT, pw2T};
            src = srcs[wsel]; dst = dsts[wsel];
            R = 512; Cc = 512; c0 = (local & 7) * 64; r0 = (local >> 3) * 64;
        } else if (lcl < 576) {
            const int local = lcl - 320;
            src = w1; dst = w1T; R = 1024; Cc = 1024;
            c0 = (local & 15) * 64; r0 = (local >> 4) * 64;
        } else {
            const int local = lcl - 576;
            src = w2; dst = w2T; R = 1024; Cc = 512;
            c0 = (local & 7) * 64; r0 = (local >> 3) * 64;
        }
    }
#pragma unroll
    for (int i = 0; i < 4; i++) {
        const int r = (t >> 4) + i * 16;
        const int c = (t & 15) * 4;
        const float4 v = *(const float4*)&src[(size_t)(r0 + r) * Cc + c0 + c];
        tile[r][c + 0] = v.x; tile[r][c + 1] = v.y;
        tile[r][c + 2] = v.z; tile[r][c + 3] = v.w;
    }
    __syncthreads();
#pragma unroll
    for (int i = 0; i < 2; i++) {
        const int c = (t >> 3) + i * 32;
        const int rs = (t & 7) * 8;
        short8 o;
#pragma unroll
        for (int j = 0; j < 8; j++) o[j] = (short)f2b(tile[rs + j][c]);
        *(short8*)&dst[(size_t)(c0 + c) * R + r0 + rs] = o;
    }
}

// ---------------------------------------------------------------------------
// KV partials: grid (8 ksplit, 8 h, 8 b) = 512 blocks, 2/CU.
// ---------------------------------------------------------------------------
__global__ __launch_bounds__(256)
void kv_partial(const ushort_t* __restrict__ Kp, const ushort_t* __restrict__ V,
                float* __restrict__ KVp, float* __restrict__ Ksp)
{
    __shared__ ushort_t Ks[256 * 64];
    __shared__ ushort_t Vs[256 * 64];
    const int t = threadIdx.x;
    const int sp = blockIdx.x, h = blockIdx.y, b = blockIdx.z;
    const int d0 = t >> 2, e0 = (t & 3) * 16;
    const int srow = t >> 3, scol = (t & 7) * 8;
    float acc[16] = {};
    float ksum = 0.f;
    for (int c = 0; c < 2; c++) {
        if (c) __syncthreads();
        const size_t sbase = (size_t)b * 4096 + sp * 512 + c * 256;
#pragma unroll
        for (int i = 0; i < 8; i++) {
            const size_t go = (sbase + i * 32 + srow) * 512 + h * 64 + scol;
            gload16(Kp + go, (void*)(&Ks[i * 2048] + t * 8));
            gload16(V + go, (void*)(&Vs[i * 2048] + t * 8));
        }
        __syncthreads();
        for (int s = 0; s < 256; s++) {
            const float k = b2f(Ks[s * 64 + d0]);
            if ((t & 3) == 0) ksum += k;
            const short8 v0 = *(const short8*)&Vs[s * 64 + e0];
            const short8 v1 = *(const short8*)&Vs[s * 64 + e0 + 8];
#pragma unroll
            for (int j = 0; j < 8; j++) {
                acc[j]     += k * b2f((unsigned short)v0[j]);
                acc[8 + j] += k * b2f((unsigned short)v1[j]);
            }
        }
    }
    const int bh = b * 8 + h;
    float* kvo = KVp + (((size_t)sp * 64 + bh) * 64 + d0) * 64 + e0;
#pragma unroll
    for (int j = 0; j < 16; j++) kvo[j] = acc[j];
    if ((t & 3) == 0) Ksp[((size_t)sp * 64 + bh) * 64 + d0] = ksum;
}

// KVt[bh][80][64]: rows 0-63 = KV[e][d], row 64 = Ksum[d], rows 65-79 = 0
__global__ __launch_bounds__(256)
void kv_finalize(const float* __restrict__ KVp, const float* __restrict__ Ksp,
                 ushort_t* __restrict__ KVt)
{
    const int bh = blockIdx.x, t = threadIdx.x;
    ushort_t* o = KVt + (size_t)bh * 5120;
#pragma unroll
    for (int i = 0; i < 16; i++) {
        const int idx = i * 256 + t;
        const int e = idx >> 6, d = idx & 63;
        float s = 0.f;
#pragma unroll
        for (int sp = 0; sp < 8; sp++)
            s += KVp[(((size_t)sp * 64 + bh) * 64 + d) * 64 + e];
        o[idx] = f2b(s);
    }
    if (t < 64) {
        float s = 0.f;
#pragma unroll
        for (int sp = 0; sp < 8; sp++) s += Ksp[((size_t)sp * 64 + bh) * 64 + t];
        o[4096 + t] = f2b(s);
    }
    for (int idx = 4160 + t; idx < 5120; idx += 256) o[idx] = 0;
}

// msg1[row][h*64+e] = (Qp[row] @ KV) * 1/(Qp[row].Ksum + eps)
__global__ __launch_bounds__(256, 2)
void attn_apply(const ushort_t* __restrict__ Qp, const ushort_t* __restrict__ KVt,
                ushort_t* __restrict__ msg1)
{
    __shared__ ushort_t As[256 * 64];
    __shared__ ushort_t Bs[80 * 64];
    const int t = threadIdx.x;
    const int ch = blockIdx.x, h = blockIdx.y, b = blockIdx.z;
    const int w = t >> 6, l = t & 63;
    const int lr = l & 15, lg = l >> 4;
    const int row0 = ch * 256;
    const int srow = t >> 3;
    const int sc = ((t & 7) ^ (srow & 7)) * 8;
    const ushort_t* kv = KVt + (size_t)(b * 8 + h) * 5120;
#pragma unroll
    for (int i = 0; i < 2; i++)
        gload16(kv + (size_t)(i * 32 + srow) * 64 + sc,
                (void*)(&Bs[i * 2048] + t * 8));
    if (t < 128)
        gload16(kv + (size_t)(64 + srow) * 64 + sc,
                (void*)(&Bs[4096] + t * 8));
    const ushort_t* qb = Qp + ((size_t)b * 8192 + row0) * 512 + h * 64;
#pragma unroll
    for (int i = 0; i < 8; i++)
        gload16(qb + (size_t)(i * 32 + srow) * 512 + sc,
                (void*)(&As[i * 2048] + t * 8));
    __syncthreads();
    f32x4 acc[4][5] = {};
    const int wr = w * 64;
#pragma unroll
    for (int ks = 0; ks < 2; ks++) {
        const int kswz = ((ks * 4 + lg) ^ (lr & 7)) * 8;
        short8 a[4], bb[5];
#pragma unroll
        for (int mf = 0; mf < 4; mf++)
            a[mf] = *(const short8*)&As[(wr + mf * 16 + lr) * 64 + kswz];
#pragma unroll
        for (int nf = 0; nf < 5; nf++)
            bb[nf] = *(const short8*)&Bs[(nf * 16 + lr) * 64 + kswz];
#pragma unroll
        for (int mf = 0; mf < 4; mf++)
#pragma unroll
            for (int nf = 0; nf < 5; nf++)
                acc[mf][nf] = __builtin_amdgcn_mfma_f32_16x16x32_bf16(
                    a[mf], bb[nf], acc[mf][nf], 0, 0, 0);
    }
#pragma unroll
    for (int mf = 0; mf < 4; mf++) {
#pragma unroll
        for (int i = 0; i < 4; i++) {
            const int m = row0 + wr + mf * 16 + lg * 4 + i;
            const float zden = __shfl(acc[mf][4][i], (l & 48));
            const float z = 1.f / (zden + 1e-6f);
#pragma unroll
            for (int nf = 0; nf < 4; nf++) {
                const int e = nf * 16 + lr;
                msg1[((size_t)b * 8192 + m) * 512 + h * 64 + e] =
                    f2b(acc[mf][nf][i] * z);
            }
        }
    }
}

// in-place LayerNorm over rows of 512 bf16; one wave per row (LN1)
__global__ __launch_bounds__(256)
void layer_norm_k(ushort_t* __restrict__ X, const float* __restrict__ g,
                  const float* __restrict__ bta)
{
    const int t = threadIdx.x;
    const int row = blockIdx.x * 4 + (t >> 6);
    const int l = t & 63;
    ushort_t* x = X + (size_t)row * 512;
    const short8 v = *(const short8*)&x[l * 8];
    float f[8];
    float s = 0.f;
#pragma unroll
    for (int j = 0; j < 8; j++) { f[j] = b2f((unsigned short)v[j]); s += f[j]; }
#pragma unroll
    for (int o = 32; o > 0; o >>= 1) s += __shfl_xor(s, o);
    const float mean = s * (1.f / 512.f);
    float vs = 0.f;
#pragma unroll
    for (int j = 0; j < 8; j++) { const float d = f[j] - mean; vs += d * d; }
#pragma unroll
    for (int o = 32; o > 0; o >>= 1) vs += __shfl_xor(vs, o);
    const float rstd = rsqrtf(vs * (1.f / 512.f) + 1e-5f);
    short8 ov;
#pragma unroll
    for (int j = 0; j < 8; j++) {
        const int c = l * 8 + j;
        ov[j] = (short)f2b((f[j] - mean) * rstd * g[c] + bta[c]);
    }
    *(short8*)&x[l * 8] = ov;
}

// Fused LN2 + residual + transpose
__global__ __launch_bounds__(256)
void ln2_final(const ushort_t* __restrict__ outp, const ushort_t* __restrict__ sfT,
               const float* __restrict__ g, const float* __restrict__ bta,
               float* __restrict__ out)
{
    __shared__ ushort_t tile[64][514];
    const int t = threadIdx.x;
    const int ns0 = blockIdx.x * 64, b = blockIdx.y;
    const int w = t >> 6, l = t & 63;
#pragma unroll
    for (int rr = 0; rr < 16; rr++) {
        const int r = w * 16 + rr;
        const size_t grow = (size_t)b * 8192 + ns0 + r;
        const short8 v = *(const short8*)&outp[grow * 512 + l * 8];
        float f[8];
        float s = 0.f;
#pragma unroll
        for (int j = 0; j < 8; j++) { f[j] = b2f((unsigned short)v[j]); s += f[j]; }
#pragma unroll
        for (int o = 32; o > 0; o >>= 1) s += __shfl_xor(s, o);
        const float mean = s * (1.f / 512.f);
        float vs = 0.f;
#pragma unroll
        for (int j = 0; j < 8; j++) { const float d = f[j] - mean; vs += d * d; }
#pragma unroll
        for (int o = 32; o > 0; o >>= 1) vs += __shfl_xor(vs, o);
        const float rstd = rsqrtf(vs * (1.f / 512.f) + 1e-5f);
        const short8 sv = *(const short8*)&sfT[grow * 512 + l * 8];
        short8 ov;
#pragma unroll
        for (int j = 0; j < 8; j++) {
            const int c = l * 8 + j;
            ov[j] = (short)f2b(b2f((unsigned short)sv[j]) +
                               (f[j] - mean) * rstd * g[c] + bta[c]);
        }
        *(short8*)&tile[r][l * 8] = ov;
    }
    __syncthreads();
#pragma unroll
    for (int i = 0; i < 32; i++) {
        const int d = (t >> 4) + i * 16;
        const int nss = (t & 15) * 4;
        float4 o;
        o.x = b2f(tile[nss + 0][d]);
        o.y = b2f(tile[nss + 1][d]);
        o.z = b2f(tile[nss + 2][d]);
        o.w = b2f(tile[nss + 3][d]);
        *(float4*)&out[((size_t)b * 512 + d) * 8192 + ns0 + nss] = o;
    }
}

// ---------------------------------------------------------------------------
extern "C" void kernel_launch(void* const* d_in, const int* in_sizes, int n_in,
                              void* d_out, int out_size, void* d_ws, size_t ws_size,
                              hipStream_t stream)
{
    (void)in_sizes; (void)n_in; (void)out_size; (void)ws_size;
    const float* search_feat   = (const float*)d_in[0];
    const float* template_feat = (const float*)d_in[2];
    const float* template_xyz  = (const float*)d_in[3];
    const float* pos_w1  = (const float*)d_in[4];
    const float* pos_b1  = (const float*)d_in[5];
    const float* pos_w2  = (const float*)d_in[6];
    const float* pos_b2  = (const float*)d_in[7];
    const float* wq      = (const float*)d_in[8];
    const float* wk      = (const float*)d_in[9];
    const float* wv      = (const float*)d_in[10];
    const float* w_merge = (const float*)d_in[11];
    const float* mlp_w1  = (const float*)d_in[12];
    const float* mlp_w2  = (const float*)d_in[13];
    const float* ln1_g   = (const float*)d_in[14];
    const float* ln1_b   = (const float*)d_in[15];
    const float* ln2_g   = (const float*)d_in[16];
    const float* ln2_b   = (const float*)d_in[17];
    float* out = (float*)d_out;

    char* ws = (char*)d_ws;
    ushort_t* sfT    = (ushort_t*)(ws + 0);           // [65536][512]
    ushort_t* Qp     = (ushort_t*)(ws + 67108864);    // [65536][512]; reused as outp
    ushort_t* tfT    = (ushort_t*)(ws + 134217728);   // [32768][512]
    ushort_t* Kp     = (ushort_t*)(ws + 167772160);   // [32768][512]
    ushort_t* msg2   = (ushort_t*)(ws + 134217728);   // [65536][512], overlaps tfT+Kp
    ushort_t* P1     = (ushort_t*)(ws + 201326592);   // [32768][512]
    ushort_t* Vv     = (ushort_t*)(ws + 201326592);   // reuses P1 slot
    ushort_t* tfpos  = (ushort_t*)(ws + 234881024);   // [32768][512]
    ushort_t* msg1   = (ushort_t*)(ws + 268435456);   // [65536][512]
    ushort_t* hidden = (ushort_t*)(ws + 201326592);   // [65536][1024]
    ushort_t* outp   = Qp;
    ushort_t* wqT  = (ushort_t*)(ws + 335544320);
    ushort_t* wkT  = (ushort_t*)(ws + 336068608);
    ushort_t* wvT  = (ushort_t*)(ws + 336592896);
    ushort_t* wmT  = (ushort_t*)(ws + 337117184);
    ushort_t* pw2T = (ushort_t*)(ws + 337641472);
    ushort_t* w1T  = (ushort_t*)(ws + 338165760);
    ushort_t* w2T  = (ushort_t*)(ws + 340262912);
    // KVp/Ksp live in msg1's region (dead until attn_apply writes msg1)
    float*    KVp  = (float*)(ws + 268435456);
    float*    Ksp  = (float*)(ws + 276824064);
    ushort_t* KVt  = (ushort_t*)(ws + 345571328);     // [64][80][64]

    // 1: all transposes + pos MLP
    prep<<<dim3(21184), 256, 0, stream>>>(
        search_feat, template_feat, template_xyz, pos_w1, pos_b1,
        wq, wk, wv, w_merge, pos_w2, mlp_w1, mlp_w2,
        sfT, tfT, P1, wqT, wkT, wvT, wmT, pw2T, w1T, w2T);
    // 2: G1 + G2 + G3b
    gemm_proj<<<dim3(4096), 256, 0, stream>>>(sfT, tfT, P1, wqT, wkT, pw2T,
                                              Qp, Kp, tfpos, pos_b2);
    // 3: G4 (V projection)
    gemm128<0><<<dim3(1024), 256, 0, stream>>>(tfpos, nullptr, wvT, Vv,
                                               nullptr, nullptr, 512, 512, 512, 512, 0, 4);
    // 4-6: linear attention core
    kv_partial<<<dim3(8, 8, 8), 256, 0, stream>>>(Kp, Vv, KVp, Ksp);
    kv_finalize<<<dim3(64), 256, 0, stream>>>(KVp, Ksp, KVt);
    attn_apply<<<dim3(32, 8, 8), 256, 0, stream>>>(Qp, KVt, msg1);
    // 7-8: merge + LN1
    gemm128<0><<<dim3(2048), 256, 0, stream>>>(msg1, nullptr, wmT, msg2,
                                               nullptr, nullptr, 512, 512, 512, 512, 0, 4);
    layer_norm_k<<<dim3(16384), 256, 0, stream>>>(msg2, ln1_g, ln1_b);
    // 9-10: MLP
    gemm128<3><<<dim3(4096), 256, 0, stream>>>(sfT, msg2, w1T, hidden,
                                               nullptr, nullptr, 1024, 1024, 512, 512, 512, 8);
    gemm128<0><<<dim3(2048), 256, 0, stream>>>(hidden, nullptr, w2T, outp,
                                               nullptr, nullptr, 512, 1024, 1024, 1024, 0, 4);
    // 11: fused LN2 + residual + transpose
    ln2_final<<<dim3(128, 8), 256, 0, stream>>>(outp, sfT, ln2_g, ln2_b, out);
}

// Round 14
// 647.967 us; speedup vs baseline: 1.0927x; 1.0162x over previous
//
#include <hip/hip_runtime.h>
#include <stdint.h>
#include <stddef.h>

// ---------------------------------------------------------------------------
// B=8, D=512, H=8, HD=64, NS=8192, NT=4096
// R13: GEMM frozen at R12's m97 structure (128x128, BK=64, single 32KB LDS,
// 4 waves, 2-barrier loop, 4-5 blocks/CU). Algebraic change: G3b eliminated.
//   V = (tfT + P1@pw2 + b2)@wv = tfT@wv + P1@(pw2@wv) + (b2@wv)
// wv2T = (pw2@wv)^T computed as 16 extra blocks in gemm_proj (A=wvT, W=pw2C);
// bv = b2@wv computed in prep; V is ONE dual-A dual-W GEMM with K=1024.
// ---------------------------------------------------------------------------

using ushort_t = unsigned short;
using short4v = __attribute__((ext_vector_type(4))) short;
using short8 = __attribute__((ext_vector_type(8))) short;
using f32x4  = __attribute__((ext_vector_type(4))) float;

#define DEVI __device__ __forceinline__

DEVI float b2f(unsigned short u) {
    unsigned v = ((unsigned)u) << 16;
    return __builtin_bit_cast(float, v);
}
DEVI unsigned short f2b(float x) {
    unsigned u = __builtin_bit_cast(unsigned, x);
    u += 0x7FFFu + ((u >> 16) & 1u);   // RNE
    return (unsigned short)(u >> 16);
}
DEVI void gload16(const void* g, void* l) {
    __builtin_amdgcn_global_load_lds(
        (const __attribute__((address_space(1))) unsigned*)g,
        (__attribute__((address_space(3))) unsigned*)l, 16, 0, 0);
}

// ---------------------------------------------------------------------------
// GEMM (m97 structure): C[m][n] = epi( sum_k A[m][k] * W[n][k] )
// A split (A0/A1 at K0), W split (W0/W1 at K0w). 128x128, BK=64, 4 waves,
// single 32KB LDS buffer, 2-barrier loop.
// EPI: 0=none 1=elu+1 3=relu 4=+bias[n]
// ---------------------------------------------------------------------------
template <int EPI>
__global__ __launch_bounds__(256, 4)
void gemm128(const ushort_t* __restrict__ A0, const ushort_t* __restrict__ A1,
             const ushort_t* __restrict__ W0, const ushort_t* __restrict__ W1,
             ushort_t* __restrict__ C, const float* __restrict__ bias,
             int N, int K, int K0, int lda0, int lda1,
             int K0w, int ldw0, int ldw1, int nn)
{
    __shared__ ushort_t As[128 * 64];   // 16KB
    __shared__ ushort_t Bs[128 * 64];   // 16KB
    const int tid = threadIdx.x;
    const int cpx = gridDim.x >> 3;
    const int lid = (blockIdx.x & 7) * cpx + (blockIdx.x >> 3);
    const int m0 = (lid / nn) * 128;
    const int n0 = (lid % nn) * 128;
    const int w = tid >> 6, l = tid & 63;
    const int wm = (w >> 1) * 64, wn = (w & 1) * 64;
    const int lr = l & 15, lg = l >> 4;
    const int srow = tid >> 3;                 // 0..31
    const int sck  = (tid & 7) ^ (srow & 7);   // pre-swizzled k-chunk
    const int nk = K / 64;

    f32x4 acc[4][4] = {};

    for (int t = 0; t < nk; ++t) {
        const int kb = t * 64;
        {
            const ushort_t* p; int ld;
            if (kb < K0) { p = A0 + (size_t)m0 * lda0 + kb; ld = lda0; }
            else         { p = A1 + (size_t)m0 * lda1 + (kb - K0); ld = lda1; }
            p += (size_t)srow * ld + sck * 8;
#pragma unroll
            for (int j = 0; j < 4; j++)
                gload16(p + (size_t)(j * 32) * ld, (void*)(&As[j * 2048] + tid * 8));
            const ushort_t* q; int ldw;
            if (kb < K0w) { q = W0 + (size_t)n0 * ldw0 + kb; ldw = ldw0; }
            else          { q = W1 + (size_t)n0 * ldw1 + (kb - K0w); ldw = ldw1; }
            q += (size_t)srow * ldw + sck * 8;
#pragma unroll
            for (int j = 0; j < 4; j++)
                gload16(q + (size_t)(j * 32) * ldw, (void*)(&Bs[j * 2048] + tid * 8));
        }
        asm volatile("s_waitcnt vmcnt(0)" ::: "memory");
        __builtin_amdgcn_s_barrier();
#pragma unroll
        for (int ks = 0; ks < 2; ks++) {
            short8 a[4], b[4];
#pragma unroll
            for (int mf = 0; mf < 4; mf++) {
                const int r = wm + mf * 16 + lr;
                a[mf] = *(const short8*)&As[r * 64 + ((ks * 4 + lg) ^ (r & 7)) * 8];
            }
#pragma unroll
            for (int nf = 0; nf < 4; nf++) {
                const int r = wn + nf * 16 + lr;
                b[nf] = *(const short8*)&Bs[r * 64 + ((ks * 4 + lg) ^ (r & 7)) * 8];
            }
            __builtin_amdgcn_s_setprio(1);
#pragma unroll
            for (int mf = 0; mf < 4; mf++)
#pragma unroll
                for (int nf = 0; nf < 4; nf++)
                    acc[mf][nf] = __builtin_amdgcn_mfma_f32_16x16x32_bf16(
                        a[mf], b[nf], acc[mf][nf], 0, 0, 0);
            __builtin_amdgcn_s_setprio(0);
        }
        __builtin_amdgcn_s_barrier();
    }

#pragma unroll
    for (int mf = 0; mf < 4; mf++) {
#pragma unroll
        for (int i = 0; i < 4; i++) {
            const int m = m0 + wm + mf * 16 + lg * 4 + i;
#pragma unroll
            for (int nf = 0; nf < 4; nf++) {
                const int n = n0 + wn + nf * 16 + lr;
                float x = acc[mf][nf][i];
                if constexpr (EPI == 1) { x = x > 0.f ? x + 1.f : __expf(x); }
                if constexpr (EPI == 3) { x = fmaxf(x, 0.f); }
                if constexpr (EPI == 4) { x += bias[n]; }
                C[(size_t)m * N + n] = f2b(x);
            }
        }
    }
}

// ---------------------------------------------------------------------------
// gemm_proj: G1 (Qp=elu(sfT@wq)+1, [0,2048)) + G2 (Kp=elu(tfT@wk)+1,
// [2048,3072)) + wv2T (=(pw2@wv)^T = wvT@pw2C, [3072,3088)). K=512, nn=4.
// ---------------------------------------------------------------------------
__global__ __launch_bounds__(256, 4)
void gemm_proj(const ushort_t* __restrict__ sfT, const ushort_t* __restrict__ tfT,
               const ushort_t* __restrict__ wvT, const ushort_t* __restrict__ pw2C,
               const ushort_t* __restrict__ wqT, const ushort_t* __restrict__ wkT,
               ushort_t* __restrict__ Qp, ushort_t* __restrict__ Kp,
               ushort_t* __restrict__ wv2T)
{
    __shared__ ushort_t As[128 * 64];
    __shared__ ushort_t Bs[128 * 64];
    const int tid = threadIdx.x;
    const int cpx = gridDim.x >> 3;
    const int lid = (blockIdx.x & 7) * cpx + (blockIdx.x >> 3);
    const ushort_t* A0; const ushort_t* Wt; ushort_t* C; int loc; bool doElu;
    if (lid < 2048)      { loc = lid;        A0 = sfT; Wt = wqT;  C = Qp;   doElu = true; }
    else if (lid < 3072) { loc = lid - 2048; A0 = tfT; Wt = wkT;  C = Kp;   doElu = true; }
    else                 { loc = lid - 3072; A0 = wvT; Wt = pw2C; C = wv2T; doElu = false; }
    const int m0 = (loc >> 2) * 128;
    const int n0 = (loc & 3) * 128;
    const int w = tid >> 6, l = tid & 63;
    const int wm = (w >> 1) * 64, wn = (w & 1) * 64;
    const int lr = l & 15, lg = l >> 4;
    const int srow = tid >> 3;
    const int sck  = (tid & 7) ^ (srow & 7);

    f32x4 acc[4][4] = {};

    for (int t = 0; t < 8; ++t) {
        const int kb = t * 64;
        {
            const ushort_t* p = A0 + (size_t)(m0 + srow) * 512 + kb + sck * 8;
#pragma unroll
            for (int j = 0; j < 4; j++)
                gload16(p + (size_t)(j * 32) * 512, (void*)(&As[j * 2048] + tid * 8));
            const ushort_t* q = Wt + (size_t)(n0 + srow) * 512 + kb + sck * 8;
#pragma unroll
            for (int j = 0; j < 4; j++)
                gload16(q + (size_t)(j * 32) * 512, (void*)(&Bs[j * 2048] + tid * 8));
        }
        asm volatile("s_waitcnt vmcnt(0)" ::: "memory");
        __builtin_amdgcn_s_barrier();
#pragma unroll
        for (int ks = 0; ks < 2; ks++) {
            short8 a[4], b[4];
#pragma unroll
            for (int mf = 0; mf < 4; mf++) {
                const int r = wm + mf * 16 + lr;
                a[mf] = *(const short8*)&As[r * 64 + ((ks * 4 + lg) ^ (r & 7)) * 8];
            }
#pragma unroll
            for (int nf = 0; nf < 4; nf++) {
                const int r = wn + nf * 16 + lr;
                b[nf] = *(const short8*)&Bs[r * 64 + ((ks * 4 + lg) ^ (r & 7)) * 8];
            }
            __builtin_amdgcn_s_setprio(1);
#pragma unroll
            for (int mf = 0; mf < 4; mf++)
#pragma unroll
                for (int nf = 0; nf < 4; nf++)
                    acc[mf][nf] = __builtin_amdgcn_mfma_f32_16x16x32_bf16(
                        a[mf], b[nf], acc[mf][nf], 0, 0, 0);
            __builtin_amdgcn_s_setprio(0);
        }
        __builtin_amdgcn_s_barrier();
    }

#pragma unroll
    for (int mf = 0; mf < 4; mf++) {
#pragma unroll
        for (int i = 0; i < 4; i++) {
            const int m = m0 + wm + mf * 16 + lg * 4 + i;
#pragma unroll
            for (int nf = 0; nf < 4; nf++) {
                const int n = n0 + wn + nf * 16 + lr;
                float x = acc[mf][nf][i];
                if (doElu) x = x > 0.f ? x + 1.f : __expf(x);
                C[(size_t)m * 512 + n] = f2b(x);
            }
        }
    }
}

// ---------------------------------------------------------------------------
// prep: transposes + pos MLP + pw2C cast + bv, one launch. Ranges:
// [0,8192): sfT  [8192,12288): tfT
// [12288,12544): wq/wk/wv/wm transposes  [12544,12608): pw2C cast
// [12608,12864): w1T  [12864,12992): w2T
// [12992,21184): pos MLP  [21184,21186): bv = b2@wv
// ---------------------------------------------------------------------------
__global__ __launch_bounds__(256)
void prep(const float* __restrict__ sfeat, const float* __restrict__ tfeat,
          const float* __restrict__ xyz, const float* __restrict__ pw1,
          const float* __restrict__ pb1, const float* __restrict__ pb2,
          const float* wq, const float* wk, const float* wvf, const float* wm,
          const float* pw2, const float* w1, const float* w2,
          ushort_t* sfT, ushort_t* tfT, ushort_t* P1,
          ushort_t* wqT, ushort_t* wkT, ushort_t* wvT, ushort_t* wmT,
          ushort_t* pw2C, ushort_t* w1T, ushort_t* w2T, float* bv)
{
    const int bid = blockIdx.x;
    const int t = threadIdx.x;
    if (bid >= 21184) {   // bv[n] = sum_j b2[j] * wv[j][n]
        const int n = (bid - 21184) * 256 + t;
        float a = 0.f;
        for (int j = 0; j < 512; j++) a += pb2[j] * wvf[(size_t)j * 512 + n];
        bv[n] = a;
        return;
    }
    if (bid >= 12992) {   // pos MLP: 4 rows per block
        const int m = (bid - 12992) * 4 + (t >> 6);
        const int n0 = (t & 63) * 8;
        const float x = xyz[m * 3 + 0], y = xyz[m * 3 + 1], z = xyz[m * 3 + 2];
        short8 o;
#pragma unroll
        for (int j = 0; j < 8; j++) {
            const int n = n0 + j;
            float v = x * pw1[n] + y * pw1[512 + n] + z * pw1[1024 + n] + pb1[n];
            o[j] = (short)f2b(fmaxf(v, 0.f));
        }
        *(short8*)&P1[(size_t)m * 512 + n0] = o;
        return;
    }
    if (bid >= 12544 && bid < 12608) {   // pw2C: plain f32->bf16 cast (no transpose)
        const int local = bid - 12544;
        const int r0 = (local >> 3) * 64, c0 = (local & 7) * 64;
#pragma unroll
        for (int i = 0; i < 4; i++) {
            const int r = r0 + (t >> 4) + i * 16;
            const int c = c0 + (t & 15) * 4;
            const float4 v = *(const float4*)&pw2[(size_t)r * 512 + c];
            short4v o;
            o[0] = (short)f2b(v.x); o[1] = (short)f2b(v.y);
            o[2] = (short)f2b(v.z); o[3] = (short)f2b(v.w);
            *(short4v*)&pw2C[(size_t)r * 512 + c] = o;
        }
        return;
    }
    __shared__ float tile[64][65];
    const float* src; ushort_t* dst; int R, Cc, c0, r0;
    if (bid < 8192) {
        const int b = bid >> 10, rem = bid & 1023;
        src = sfeat + (size_t)b * 512 * 8192; dst = sfT + (size_t)b * 512 * 8192;
        R = 512; Cc = 8192; c0 = (rem & 127) * 64; r0 = (rem >> 7) * 64;
    } else if (bid < 12288) {
        const int lcl = bid - 8192; const int b = lcl >> 9, rem = lcl & 511;
        src = tfeat + (size_t)b * 512 * 4096; dst = tfT + (size_t)b * 512 * 4096;
        R = 512; Cc = 4096; c0 = (rem & 63) * 64; r0 = (rem >> 6) * 64;
    } else if (bid < 12544) {
        const int lcl = bid - 12288;
        const int wsel = lcl >> 6, local = lcl & 63;
        const float* srcs[4] = {wq, wk, wvf, wm};
        ushort_t* dsts[4] = {wqT, wkT, wvT, wmT};
        src = srcs[wsel]; dst = dsts[wsel];
        R = 512; Cc = 512; c0 = (local & 7) * 64; r0 = (local >> 3) * 64;
    } else if (bid < 12864) {
        const int local = bid - 12608;
        src = w1; dst = w1T; R = 1024; Cc = 1024;
        c0 = (local & 15) * 64; r0 = (local >> 4) * 64;
    } else {
        const int local = bid - 12864;
        src = w2; dst = w2T; R = 1024; Cc = 512;
        c0 = (local & 7) * 64; r0 = (local >> 3) * 64;
    }
#pragma unroll
    for (int i = 0; i < 4; i++) {
        const int r = (t >> 4) + i * 16;
        const int c = (t & 15) * 4;
        const float4 v = *(const float4*)&src[(size_t)(r0 + r) * Cc + c0 + c];
        tile[r][c + 0] = v.x; tile[r][c + 1] = v.y;
        tile[r][c + 2] = v.z; tile[r][c + 3] = v.w;
    }
    __syncthreads();
#pragma unroll
    for (int i = 0; i < 2; i++) {
        const int c = (t >> 3) + i * 32;
        const int rs = (t & 7) * 8;
        short8 o;
#pragma unroll
        for (int j = 0; j < 8; j++) o[j] = (short)f2b(tile[rs + j][c]);
        *(short8*)&dst[(size_t)(c0 + c) * R + r0 + rs] = o;
    }
}

// ---------------------------------------------------------------------------
// KV partials: grid (8 ksplit, 8 h, 8 b) = 512 blocks, 2/CU.
// ---------------------------------------------------------------------------
__global__ __launch_bounds__(256)
void kv_partial(const ushort_t* __restrict__ Kp, const ushort_t* __restrict__ V,
                float* __restrict__ KVp, float* __restrict__ Ksp)
{
    __shared__ ushort_t Ks[256 * 64];
    __shared__ ushort_t Vs[256 * 64];
    const int t = threadIdx.x;
    const int sp = blockIdx.x, h = blockIdx.y, b = blockIdx.z;
    const int d0 = t >> 2, e0 = (t & 3) * 16;
    const int srow = t >> 3, scol = (t & 7) * 8;
    float acc[16] = {};
    float ksum = 0.f;
    for (int c = 0; c < 2; c++) {
        if (c) __syncthreads();
        const size_t sbase = (size_t)b * 4096 + sp * 512 + c * 256;
#pragma unroll
        for (int i = 0; i < 8; i++) {
            const size_t go = (sbase + i * 32 + srow) * 512 + h * 64 + scol;
            gload16(Kp + go, (void*)(&Ks[i * 2048] + t * 8));
            gload16(V + go, (void*)(&Vs[i * 2048] + t * 8));
        }
        __syncthreads();
        for (int s = 0; s < 256; s++) {
            const float k = b2f(Ks[s * 64 + d0]);
            if ((t & 3) == 0) ksum += k;
            const short8 v0 = *(const short8*)&Vs[s * 64 + e0];
            const short8 v1 = *(const short8*)&Vs[s * 64 + e0 + 8];
#pragma unroll
            for (int j = 0; j < 8; j++) {
                acc[j]     += k * b2f((unsigned short)v0[j]);
                acc[8 + j] += k * b2f((unsigned short)v1[j]);
            }
        }
    }
    const int bh = b * 8 + h;
    float* kvo = KVp + (((size_t)sp * 64 + bh) * 64 + d0) * 64 + e0;
#pragma unroll
    for (int j = 0; j < 16; j++) kvo[j] = acc[j];
    if ((t & 3) == 0) Ksp[((size_t)sp * 64 + bh) * 64 + d0] = ksum;
}

// KVt[bh][80][64]: rows 0-63 = KV[e][d], row 64 = Ksum[d], rows 65-79 = 0
__global__ __launch_bounds__(256)
void kv_finalize(const float* __restrict__ KVp, const float* __restrict__ Ksp,
                 ushort_t* __restrict__ KVt)
{
    const int bh = blockIdx.x, t = threadIdx.x;
    ushort_t* o = KVt + (size_t)bh * 5120;
#pragma unroll
    for (int i = 0; i < 16; i++) {
        const int idx = i * 256 + t;
        const int e = idx >> 6, d = idx & 63;
        float s = 0.f;
#pragma unroll
        for (int sp = 0; sp < 8; sp++)
            s += KVp[(((size_t)sp * 64 + bh) * 64 + d) * 64 + e];
        o[idx] = f2b(s);
    }
    if (t < 64) {
        float s = 0.f;
#pragma unroll
        for (int sp = 0; sp < 8; sp++) s += Ksp[((size_t)sp * 64 + bh) * 64 + t];
        o[4096 + t] = f2b(s);
    }
    for (int idx = 4160 + t; idx < 5120; idx += 256) o[idx] = 0;
}

// msg1[row][h*64+e] = (Qp[row] @ KV) * 1/(Qp[row].Ksum + eps)
__global__ __launch_bounds__(256, 2)
void attn_apply(const ushort_t* __restrict__ Qp, const ushort_t* __restrict__ KVt,
                ushort_t* __restrict__ msg1)
{
    __shared__ ushort_t As[256 * 64];
    __shared__ ushort_t Bs[80 * 64];
    const int t = threadIdx.x;
    const int ch = blockIdx.x, h = blockIdx.y, b = blockIdx.z;
    const int w = t >> 6, l = t & 63;
    const int lr = l & 15, lg = l >> 4;
    const int row0 = ch * 256;
    const int srow = t >> 3;
    const int sc = ((t & 7) ^ (srow & 7)) * 8;
    const ushort_t* kv = KVt + (size_t)(b * 8 + h) * 5120;
#pragma unroll
    for (int i = 0; i < 2; i++)
        gload16(kv + (size_t)(i * 32 + srow) * 64 + sc,
                (void*)(&Bs[i * 2048] + t * 8));
    if (t < 128)
        gload16(kv + (size_t)(64 + srow) * 64 + sc,
                (void*)(&Bs[4096] + t * 8));
    const ushort_t* qb = Qp + ((size_t)b * 8192 + row0) * 512 + h * 64;
#pragma unroll
    for (int i = 0; i < 8; i++)
        gload16(qb + (size_t)(i * 32 + srow) * 512 + sc,
                (void*)(&As[i * 2048] + t * 8));
    __syncthreads();
    f32x4 acc[4][5] = {};
    const int wr = w * 64;
#pragma unroll
    for (int ks = 0; ks < 2; ks++) {
        const int kswz = ((ks * 4 + lg) ^ (lr & 7)) * 8;
        short8 a[4], bb[5];
#pragma unroll
        for (int mf = 0; mf < 4; mf++)
            a[mf] = *(const short8*)&As[(wr + mf * 16 + lr) * 64 + kswz];
#pragma unroll
        for (int nf = 0; nf < 5; nf++)
            bb[nf] = *(const short8*)&Bs[(nf * 16 + lr) * 64 + kswz];
#pragma unroll
        for (int mf = 0; mf < 4; mf++)
#pragma unroll
            for (int nf = 0; nf < 5; nf++)
                acc[mf][nf] = __builtin_amdgcn_mfma_f32_16x16x32_bf16(
                    a[mf], bb[nf], acc[mf][nf], 0, 0, 0);
    }
#pragma unroll
    for (int mf = 0; mf < 4; mf++) {
#pragma unroll
        for (int i = 0; i < 4; i++) {
            const int m = row0 + wr + mf * 16 + lg * 4 + i;
            const float zden = __shfl(acc[mf][4][i], (l & 48));
            const float z = 1.f / (zden + 1e-6f);
#pragma unroll
            for (int nf = 0; nf < 4; nf++) {
                const int e = nf * 16 + lr;
                msg1[((size_t)b * 8192 + m) * 512 + h * 64 + e] =
                    f2b(acc[mf][nf][i] * z);
            }
        }
    }
}

// in-place LayerNorm over rows of 512 bf16; one wave per row (LN1)
__global__ __launch_bounds__(256)
void layer_norm_k(ushort_t* __restrict__ X, const float* __restrict__ g,
                  const float* __restrict__ bta)
{
    const int t = threadIdx.x;
    const int row = blockIdx.x * 4 + (t >> 6);
    const int l = t & 63;
    ushort_t* x = X + (size_t)row * 512;
    const short8 v = *(const short8*)&x[l * 8];
    float f[8];
    float s = 0.f;
#pragma unroll
    for (int j = 0; j < 8; j++) { f[j] = b2f((unsigned short)v[j]); s += f[j]; }
#pragma unroll
    for (int o = 32; o > 0; o >>= 1) s += __shfl_xor(s, o);
    const float mean = s * (1.f / 512.f);
    float vs = 0.f;
#pragma unroll
    for (int j = 0; j < 8; j++) { const float d = f[j] - mean; vs += d * d; }
#pragma unroll
    for (int o = 32; o > 0; o >>= 1) vs += __shfl_xor(vs, o);
    const float rstd = rsqrtf(vs * (1.f / 512.f) + 1e-5f);
    short8 ov;
#pragma unroll
    for (int j = 0; j < 8; j++) {
        const int c = l * 8 + j;
        ov[j] = (short)f2b((f[j] - mean) * rstd * g[c] + bta[c]);
    }
    *(short8*)&x[l * 8] = ov;
}

// Fused LN2 + residual + transpose
__global__ __launch_bounds__(256)
void ln2_final(const ushort_t* __restrict__ outp, const ushort_t* __restrict__ sfT,
               const float* __restrict__ g, const float* __restrict__ bta,
               float* __restrict__ out)
{
    __shared__ ushort_t tile[64][514];
    const int t = threadIdx.x;
    const int ns0 = blockIdx.x * 64, b = blockIdx.y;
    const int w = t >> 6, l = t & 63;
#pragma unroll
    for (int rr = 0; rr < 16; rr++) {
        const int r = w * 16 + rr;
        const size_t grow = (size_t)b * 8192 + ns0 + r;
        const short8 v = *(const short8*)&outp[grow * 512 + l * 8];
        float f[8];
        float s = 0.f;
#pragma unroll
        for (int j = 0; j < 8; j++) { f[j] = b2f((unsigned short)v[j]); s += f[j]; }
#pragma unroll
        for (int o = 32; o > 0; o >>= 1) s += __shfl_xor(s, o);
        const float mean = s * (1.f / 512.f);
        float vs = 0.f;
#pragma unroll
        for (int j = 0; j < 8; j++) { const float d = f[j] - mean; vs += d * d; }
#pragma unroll
        for (int o = 32; o > 0; o >>= 1) vs += __shfl_xor(vs, o);
        const float rstd = rsqrtf(vs * (1.f / 512.f) + 1e-5f);
        const short8 sv = *(const short8*)&sfT[grow * 512 + l * 8];
        short8 ov;
#pragma unroll
        for (int j = 0; j < 8; j++) {
            const int c = l * 8 + j;
            ov[j] = (short)f2b(b2f((unsigned short)sv[j]) +
                               (f[j] - mean) * rstd * g[c] + bta[c]);
        }
        *(short8*)&tile[r][l * 8] = ov;
    }
    __syncthreads();
#pragma unroll
    for (int i = 0; i < 32; i++) {
        const int d = (t >> 4) + i * 16;
        const int nss = (t & 15) * 4;
        float4 o;
        o.x = b2f(tile[nss + 0][d]);
        o.y = b2f(tile[nss + 1][d]);
        o.z = b2f(tile[nss + 2][d]);
        o.w = b2f(tile[nss + 3][d]);
        *(float4*)&out[((size_t)b * 512 + d) * 8192 + ns0 + nss] = o;
    }
}

// ---------------------------------------------------------------------------
extern "C" void kernel_launch(void* const* d_in, const int* in_sizes, int n_in,
                              void* d_out, int out_size, void* d_ws, size_t ws_size,
                              hipStream_t stream)
{
    (void)in_sizes; (void)n_in; (void)out_size; (void)ws_size;
    const float* search_feat   = (const float*)d_in[0];
    const float* template_feat = (const float*)d_in[2];
    const float* template_xyz  = (const float*)d_in[3];
    const float* pos_w1  = (const float*)d_in[4];
    const float* pos_b1  = (const float*)d_in[5];
    const float* pos_w2  = (const float*)d_in[6];
    const float* pos_b2  = (const float*)d_in[7];
    const float* wq      = (const float*)d_in[8];
    const float* wk      = (const float*)d_in[9];
    const float* wv      = (const float*)d_in[10];
    const float* w_merge = (const float*)d_in[11];
    const float* mlp_w1  = (const float*)d_in[12];
    const float* mlp_w2  = (const float*)d_in[13];
    const float* ln1_g   = (const float*)d_in[14];
    const float* ln1_b   = (const float*)d_in[15];
    const float* ln2_g   = (const float*)d_in[16];
    const float* ln2_b   = (const float*)d_in[17];
    float* out = (float*)d_out;

    char* ws = (char*)d_ws;
    ushort_t* sfT    = (ushort_t*)(ws + 0);           // [65536][512]
    ushort_t* Qp     = (ushort_t*)(ws + 67108864);    // [65536][512]; reused as outp
    ushort_t* tfT    = (ushort_t*)(ws + 134217728);   // [32768][512]
    ushort_t* Kp     = (ushort_t*)(ws + 167772160);   // [32768][512]
    ushort_t* msg2   = (ushort_t*)(ws + 134217728);   // [65536][512], overlaps tfT+Kp
    ushort_t* P1     = (ushort_t*)(ws + 201326592);   // [32768][512]
    ushort_t* Vv     = (ushort_t*)(ws + 234881024);   // [32768][512] (old tfpos slot)
    ushort_t* msg1   = (ushort_t*)(ws + 268435456);   // [65536][512]
    ushort_t* hidden = (ushort_t*)(ws + 201326592);   // [65536][1024]
    ushort_t* outp   = Qp;
    ushort_t* wqT  = (ushort_t*)(ws + 335544320);
    ushort_t* wkT  = (ushort_t*)(ws + 336068608);
    ushort_t* wvT  = (ushort_t*)(ws + 336592896);
    ushort_t* wmT  = (ushort_t*)(ws + 337117184);
    ushort_t* wv2T = (ushort_t*)(ws + 337641472);     // (pw2@wv)^T  [512][512]
    ushort_t* w1T  = (ushort_t*)(ws + 338165760);
    ushort_t* w2T  = (ushort_t*)(ws + 340262912);
    ushort_t* pw2C = (ushort_t*)(ws + 341311488);     // bf16 cast of pw2 [512][512]
    float*    bv   = (float*)(ws + 342097920);        // b2@wv [512]
    // KVp/Ksp live in msg1's region (dead until attn_apply writes msg1)
    float*    KVp  = (float*)(ws + 268435456);
    float*    Ksp  = (float*)(ws + 276824064);
    ushort_t* KVt  = (ushort_t*)(ws + 345571328);     // [64][80][64]

    // 1: all transposes + pos MLP + pw2C cast + bv
    prep<<<dim3(21186), 256, 0, stream>>>(
        search_feat, template_feat, template_xyz, pos_w1, pos_b1, pos_b2,
        wq, wk, wv, w_merge, pos_w2, mlp_w1, mlp_w2,
        sfT, tfT, P1, wqT, wkT, wvT, wmT, pw2C, w1T, w2T, bv);
    // 2: G1 + G2 + wv2T
    gemm_proj<<<dim3(3088), 256, 0, stream>>>(sfT, tfT, wvT, pw2C, wqT, wkT,
                                              Qp, Kp, wv2T);
    // 3: fused V = tfT@wv + P1@wv2 + bv   (dual-A, dual-W, K=1024)
    gemm128<4><<<dim3(1024), 256, 0, stream>>>(tfT, P1, wvT, wv2T, Vv, bv,
                                               512, 1024, 512, 512, 512,
                                               512, 512, 512, 4);
    // 4-6: linear attention core
    kv_partial<<<dim3(8, 8, 8), 256, 0, stream>>>(Kp, Vv, KVp, Ksp);
    kv_finalize<<<dim3(64), 256, 0, stream>>>(KVp, Ksp, KVt);
    attn_apply<<<dim3(32, 8, 8), 256, 0, stream>>>(Qp, KVt, msg1);
    // 7-8: merge + LN1
    gemm128<0><<<dim3(2048), 256, 0, stream>>>(msg1, nullptr, wmT, wmT, msg2,
                                               nullptr, 512, 512, 512, 512, 0,
                                               512, 512, 512, 4);
    layer_norm_k<<<dim3(16384), 256, 0, stream>>>(msg2, ln1_g, ln1_b);
    // 9-10: MLP
    gemm128<3><<<dim3(4096), 256, 0, stream>>>(sfT, msg2, w1T, w1T, hidden,
                                               nullptr, 1024, 1024, 512, 512, 512,
                                               1024, 1024, 1024, 8);
    gemm128<0><<<dim3(2048), 256, 0, stream>>>(hidden, nullptr, w2T, w2T, outp,
                                               nullptr, 512, 1024, 1024, 1024, 1024,
                                               1024, 1024, 1024, 4);
    // 11: fused LN2 + residual + transpose
    ln2_final<<<dim3(128, 8), 256, 0, stream>>>(outp, sfT, ln2_g, ln2_b, out);
}

// Round 15
// 636.672 us; speedup vs baseline: 1.1121x; 1.0177x over previous
//
#include <hip/hip_runtime.h>
#include <stdint.h>
#include <stddef.h>

// ---------------------------------------------------------------------------
// B=8, D=512, H=8, HD=64, NS=8192, NT=4096
// R14 = R13 + kv_partial re-blocked: 4d x 4e per thread (2x ds_read_b64 +
// 8 conv + 16 FMA per s-step; LDS bytes/FMA 2.1 -> 1.0). All else frozen.
// ---------------------------------------------------------------------------

using ushort_t = unsigned short;
using short4v = __attribute__((ext_vector_type(4))) short;
using short8 = __attribute__((ext_vector_type(8))) short;
using f32x4  = __attribute__((ext_vector_type(4))) float;

#define DEVI __device__ __forceinline__

DEVI float b2f(unsigned short u) {
    unsigned v = ((unsigned)u) << 16;
    return __builtin_bit_cast(float, v);
}
DEVI unsigned short f2b(float x) {
    unsigned u = __builtin_bit_cast(unsigned, x);
    u += 0x7FFFu + ((u >> 16) & 1u);   // RNE
    return (unsigned short)(u >> 16);
}
DEVI void gload16(const void* g, void* l) {
    __builtin_amdgcn_global_load_lds(
        (const __attribute__((address_space(1))) unsigned*)g,
        (__attribute__((address_space(3))) unsigned*)l, 16, 0, 0);
}

// ---------------------------------------------------------------------------
// GEMM (m97 structure): C[m][n] = epi( sum_k A[m][k] * W[n][k] )
// A split (A0/A1 at K0), W split (W0/W1 at K0w). 128x128, BK=64, 4 waves,
// single 32KB LDS buffer, 2-barrier loop. EPI: 0=none 1=elu+1 3=relu 4=+bias
// ---------------------------------------------------------------------------
template <int EPI>
__global__ __launch_bounds__(256, 4)
void gemm128(const ushort_t* __restrict__ A0, const ushort_t* __restrict__ A1,
             const ushort_t* __restrict__ W0, const ushort_t* __restrict__ W1,
             ushort_t* __restrict__ C, const float* __restrict__ bias,
             int N, int K, int K0, int lda0, int lda1,
             int K0w, int ldw0, int ldw1, int nn)
{
    __shared__ ushort_t As[128 * 64];   // 16KB
    __shared__ ushort_t Bs[128 * 64];   // 16KB
    const int tid = threadIdx.x;
    const int cpx = gridDim.x >> 3;
    const int lid = (blockIdx.x & 7) * cpx + (blockIdx.x >> 3);
    const int m0 = (lid / nn) * 128;
    const int n0 = (lid % nn) * 128;
    const int w = tid >> 6, l = tid & 63;
    const int wm = (w >> 1) * 64, wn = (w & 1) * 64;
    const int lr = l & 15, lg = l >> 4;
    const int srow = tid >> 3;
    const int sck  = (tid & 7) ^ (srow & 7);
    const int nk = K / 64;

    f32x4 acc[4][4] = {};

    for (int t = 0; t < nk; ++t) {
        const int kb = t * 64;
        {
            const ushort_t* p; int ld;
            if (kb < K0) { p = A0 + (size_t)m0 * lda0 + kb; ld = lda0; }
            else         { p = A1 + (size_t)m0 * lda1 + (kb - K0); ld = lda1; }
            p += (size_t)srow * ld + sck * 8;
#pragma unroll
            for (int j = 0; j < 4; j++)
                gload16(p + (size_t)(j * 32) * ld, (void*)(&As[j * 2048] + tid * 8));
            const ushort_t* q; int ldw;
            if (kb < K0w) { q = W0 + (size_t)n0 * ldw0 + kb; ldw = ldw0; }
            else          { q = W1 + (size_t)n0 * ldw1 + (kb - K0w); ldw = ldw1; }
            q += (size_t)srow * ldw + sck * 8;
#pragma unroll
            for (int j = 0; j < 4; j++)
                gload16(q + (size_t)(j * 32) * ldw, (void*)(&Bs[j * 2048] + tid * 8));
        }
        asm volatile("s_waitcnt vmcnt(0)" ::: "memory");
        __builtin_amdgcn_s_barrier();
#pragma unroll
        for (int ks = 0; ks < 2; ks++) {
            short8 a[4], b[4];
#pragma unroll
            for (int mf = 0; mf < 4; mf++) {
                const int r = wm + mf * 16 + lr;
                a[mf] = *(const short8*)&As[r * 64 + ((ks * 4 + lg) ^ (r & 7)) * 8];
            }
#pragma unroll
            for (int nf = 0; nf < 4; nf++) {
                const int r = wn + nf * 16 + lr;
                b[nf] = *(const short8*)&Bs[r * 64 + ((ks * 4 + lg) ^ (r & 7)) * 8];
            }
            __builtin_amdgcn_s_setprio(1);
#pragma unroll
            for (int mf = 0; mf < 4; mf++)
#pragma unroll
                for (int nf = 0; nf < 4; nf++)
                    acc[mf][nf] = __builtin_amdgcn_mfma_f32_16x16x32_bf16(
                        a[mf], b[nf], acc[mf][nf], 0, 0, 0);
            __builtin_amdgcn_s_setprio(0);
        }
        __builtin_amdgcn_s_barrier();
    }

#pragma unroll
    for (int mf = 0; mf < 4; mf++) {
#pragma unroll
        for (int i = 0; i < 4; i++) {
            const int m = m0 + wm + mf * 16 + lg * 4 + i;
#pragma unroll
            for (int nf = 0; nf < 4; nf++) {
                const int n = n0 + wn + nf * 16 + lr;
                float x = acc[mf][nf][i];
                if constexpr (EPI == 1) { x = x > 0.f ? x + 1.f : __expf(x); }
                if constexpr (EPI == 3) { x = fmaxf(x, 0.f); }
                if constexpr (EPI == 4) { x += bias[n]; }
                C[(size_t)m * N + n] = f2b(x);
            }
        }
    }
}

// ---------------------------------------------------------------------------
// gemm_proj: G1 (Qp=elu(sfT@wq)+1, [0,2048)) + G2 (Kp=elu(tfT@wk)+1,
// [2048,3072)) + wv2T (=(pw2@wv)^T = wvT@pw2C, [3072,3088)). K=512, nn=4.
// ---------------------------------------------------------------------------
__global__ __launch_bounds__(256, 4)
void gemm_proj(const ushort_t* __restrict__ sfT, const ushort_t* __restrict__ tfT,
               const ushort_t* __restrict__ wvT, const ushort_t* __restrict__ pw2C,
               const ushort_t* __restrict__ wqT, const ushort_t* __restrict__ wkT,
               ushort_t* __restrict__ Qp, ushort_t* __restrict__ Kp,
               ushort_t* __restrict__ wv2T)
{
    __shared__ ushort_t As[128 * 64];
    __shared__ ushort_t Bs[128 * 64];
    const int tid = threadIdx.x;
    const int cpx = gridDim.x >> 3;
    const int lid = (blockIdx.x & 7) * cpx + (blockIdx.x >> 3);
    const ushort_t* A0; const ushort_t* Wt; ushort_t* C; int loc; bool doElu;
    if (lid < 2048)      { loc = lid;        A0 = sfT; Wt = wqT;  C = Qp;   doElu = true; }
    else if (lid < 3072) { loc = lid - 2048; A0 = tfT; Wt = wkT;  C = Kp;   doElu = true; }
    else                 { loc = lid - 3072; A0 = wvT; Wt = pw2C; C = wv2T; doElu = false; }
    const int m0 = (loc >> 2) * 128;
    const int n0 = (loc & 3) * 128;
    const int w = tid >> 6, l = tid & 63;
    const int wm = (w >> 1) * 64, wn = (w & 1) * 64;
    const int lr = l & 15, lg = l >> 4;
    const int srow = tid >> 3;
    const int sck  = (tid & 7) ^ (srow & 7);

    f32x4 acc[4][4] = {};

    for (int t = 0; t < 8; ++t) {
        const int kb = t * 64;
        {
            const ushort_t* p = A0 + (size_t)(m0 + srow) * 512 + kb + sck * 8;
#pragma unroll
            for (int j = 0; j < 4; j++)
                gload16(p + (size_t)(j * 32) * 512, (void*)(&As[j * 2048] + tid * 8));
            const ushort_t* q = Wt + (size_t)(n0 + srow) * 512 + kb + sck * 8;
#pragma unroll
            for (int j = 0; j < 4; j++)
                gload16(q + (size_t)(j * 32) * 512, (void*)(&Bs[j * 2048] + tid * 8));
        }
        asm volatile("s_waitcnt vmcnt(0)" ::: "memory");
        __builtin_amdgcn_s_barrier();
#pragma unroll
        for (int ks = 0; ks < 2; ks++) {
            short8 a[4], b[4];
#pragma unroll
            for (int mf = 0; mf < 4; mf++) {
                const int r = wm + mf * 16 + lr;
                a[mf] = *(const short8*)&As[r * 64 + ((ks * 4 + lg) ^ (r & 7)) * 8];
            }
#pragma unroll
            for (int nf = 0; nf < 4; nf++) {
                const int r = wn + nf * 16 + lr;
                b[nf] = *(const short8*)&Bs[r * 64 + ((ks * 4 + lg) ^ (r & 7)) * 8];
            }
            __builtin_amdgcn_s_setprio(1);
#pragma unroll
            for (int mf = 0; mf < 4; mf++)
#pragma unroll
                for (int nf = 0; nf < 4; nf++)
                    acc[mf][nf] = __builtin_amdgcn_mfma_f32_16x16x32_bf16(
                        a[mf], b[nf], acc[mf][nf], 0, 0, 0);
            __builtin_amdgcn_s_setprio(0);
        }
        __builtin_amdgcn_s_barrier();
    }

#pragma unroll
    for (int mf = 0; mf < 4; mf++) {
#pragma unroll
        for (int i = 0; i < 4; i++) {
            const int m = m0 + wm + mf * 16 + lg * 4 + i;
#pragma unroll
            for (int nf = 0; nf < 4; nf++) {
                const int n = n0 + wn + nf * 16 + lr;
                float x = acc[mf][nf][i];
                if (doElu) x = x > 0.f ? x + 1.f : __expf(x);
                C[(size_t)m * 512 + n] = f2b(x);
            }
        }
    }
}

// ---------------------------------------------------------------------------
// prep: transposes + pos MLP + pw2C cast + bv (ranges as in R13).
// ---------------------------------------------------------------------------
__global__ __launch_bounds__(256)
void prep(const float* __restrict__ sfeat, const float* __restrict__ tfeat,
          const float* __restrict__ xyz, const float* __restrict__ pw1,
          const float* __restrict__ pb1, const float* __restrict__ pb2,
          const float* wq, const float* wk, const float* wvf, const float* wm,
          const float* pw2, const float* w1, const float* w2,
          ushort_t* sfT, ushort_t* tfT, ushort_t* P1,
          ushort_t* wqT, ushort_t* wkT, ushort_t* wvT, ushort_t* wmT,
          ushort_t* pw2C, ushort_t* w1T, ushort_t* w2T, float* bv)
{
    const int bid = blockIdx.x;
    const int t = threadIdx.x;
    if (bid >= 21184) {   // bv[n] = sum_j b2[j] * wv[j][n]
        const int n = (bid - 21184) * 256 + t;
        float a = 0.f;
        for (int j = 0; j < 512; j++) a += pb2[j] * wvf[(size_t)j * 512 + n];
        bv[n] = a;
        return;
    }
    if (bid >= 12992) {   // pos MLP: 4 rows per block
        const int m = (bid - 12992) * 4 + (t >> 6);
        const int n0 = (t & 63) * 8;
        const float x = xyz[m * 3 + 0], y = xyz[m * 3 + 1], z = xyz[m * 3 + 2];
        short8 o;
#pragma unroll
        for (int j = 0; j < 8; j++) {
            const int n = n0 + j;
            float v = x * pw1[n] + y * pw1[512 + n] + z * pw1[1024 + n] + pb1[n];
            o[j] = (short)f2b(fmaxf(v, 0.f));
        }
        *(short8*)&P1[(size_t)m * 512 + n0] = o;
        return;
    }
    if (bid >= 12544 && bid < 12608) {   // pw2C: f32->bf16 cast (no transpose)
        const int local = bid - 12544;
        const int r0 = (local >> 3) * 64, c0 = (local & 7) * 64;
#pragma unroll
        for (int i = 0; i < 4; i++) {
            const int r = r0 + (t >> 4) + i * 16;
            const int c = c0 + (t & 15) * 4;
            const float4 v = *(const float4*)&pw2[(size_t)r * 512 + c];
            short4v o;
            o[0] = (short)f2b(v.x); o[1] = (short)f2b(v.y);
            o[2] = (short)f2b(v.z); o[3] = (short)f2b(v.w);
            *(short4v*)&pw2C[(size_t)r * 512 + c] = o;
        }
        return;
    }
    __shared__ float tile[64][65];
    const float* src; ushort_t* dst; int R, Cc, c0, r0;
    if (bid < 8192) {
        const int b = bid >> 10, rem = bid & 1023;
        src = sfeat + (size_t)b * 512 * 8192; dst = sfT + (size_t)b * 512 * 8192;
        R = 512; Cc = 8192; c0 = (rem & 127) * 64; r0 = (rem >> 7) * 64;
    } else if (bid < 12288) {
        const int lcl = bid - 8192; const int b = lcl >> 9, rem = lcl & 511;
        src = tfeat + (size_t)b * 512 * 4096; dst = tfT + (size_t)b * 512 * 4096;
        R = 512; Cc = 4096; c0 = (rem & 63) * 64; r0 = (rem >> 6) * 64;
    } else if (bid < 12544) {
        const int lcl = bid - 12288;
        const int wsel = lcl >> 6, local = lcl & 63;
        const float* srcs[4] = {wq, wk, wvf, wm};
        ushort_t* dsts[4] = {wqT, wkT, wvT, wmT};
        src = srcs[wsel]; dst = dsts[wsel];
        R = 512; Cc = 512; c0 = (local & 7) * 64; r0 = (local >> 3) * 64;
    } else if (bid < 12864) {
        const int local = bid - 12608;
        src = w1; dst = w1T; R = 1024; Cc = 1024;
        c0 = (local & 15) * 64; r0 = (local >> 4) * 64;
    } else {
        const int local = bid - 12864;
        src = w2; dst = w2T; R = 1024; Cc = 512;
        c0 = (local & 7) * 64; r0 = (local >> 3) * 64;
    }
#pragma unroll
    for (int i = 0; i < 4; i++) {
        const int r = (t >> 4) + i * 16;
        const int c = (t & 15) * 4;
        const float4 v = *(const float4*)&src[(size_t)(r0 + r) * Cc + c0 + c];
        tile[r][c + 0] = v.x; tile[r][c + 1] = v.y;
        tile[r][c + 2] = v.z; tile[r][c + 3] = v.w;
    }
    __syncthreads();
#pragma unroll
    for (int i = 0; i < 2; i++) {
        const int c = (t >> 3) + i * 32;
        const int rs = (t & 7) * 8;
        short8 o;
#pragma unroll
        for (int j = 0; j < 8; j++) o[j] = (short)f2b(tile[rs + j][c]);
        *(short8*)&dst[(size_t)(c0 + c) * R + r0 + rs] = o;
    }
}

// ---------------------------------------------------------------------------
// KV partials (R14): grid (8 ksplit, 8 h, 8 b). 4d x 4e per thread:
// d0=(t&15)*4, e0=(t>>4)*4. Per s: 2x ds_read_b64 + 8 conv + 16 FMA.
// ---------------------------------------------------------------------------
__global__ __launch_bounds__(256)
void kv_partial(const ushort_t* __restrict__ Kp, const ushort_t* __restrict__ V,
                float* __restrict__ KVp, float* __restrict__ Ksp)
{
    __shared__ ushort_t Ks[256 * 64];
    __shared__ ushort_t Vs[256 * 64];
    const int t = threadIdx.x;
    const int sp = blockIdx.x, h = blockIdx.y, b = blockIdx.z;
    const int d0 = (t & 15) * 4, e0 = (t >> 4) * 4;
    const int srow = t >> 3, scol = (t & 7) * 8;
    float acc[4][4] = {};
    float ksum[4] = {};
    for (int c = 0; c < 2; c++) {
        if (c) __syncthreads();
        const size_t sbase = (size_t)b * 4096 + sp * 512 + c * 256;
#pragma unroll
        for (int i = 0; i < 8; i++) {
            const size_t go = (sbase + i * 32 + srow) * 512 + h * 64 + scol;
            gload16(Kp + go, (void*)(&Ks[i * 2048] + t * 8));
            gload16(V + go, (void*)(&Vs[i * 2048] + t * 8));
        }
        __syncthreads();
        for (int s = 0; s < 256; s++) {
            const short4v k4 = *(const short4v*)&Ks[s * 64 + d0];
            const short4v v4 = *(const short4v*)&Vs[s * 64 + e0];
            float kf[4], vf[4];
#pragma unroll
            for (int i = 0; i < 4; i++) {
                kf[i] = b2f((unsigned short)k4[i]);
                vf[i] = b2f((unsigned short)v4[i]);
            }
#pragma unroll
            for (int i = 0; i < 4; i++)
#pragma unroll
                for (int j = 0; j < 4; j++)
                    acc[i][j] += kf[i] * vf[j];
            if (e0 == 0) {
#pragma unroll
                for (int i = 0; i < 4; i++) ksum[i] += kf[i];
            }
        }
    }
    const int bh = b * 8 + h;
#pragma unroll
    for (int i = 0; i < 4; i++) {
        float4 o; o.x = acc[i][0]; o.y = acc[i][1]; o.z = acc[i][2]; o.w = acc[i][3];
        *(float4*)&KVp[(((size_t)sp * 64 + bh) * 64 + d0 + i) * 64 + e0] = o;
    }
    if (e0 == 0) {
#pragma unroll
        for (int i = 0; i < 4; i++)
            Ksp[((size_t)sp * 64 + bh) * 64 + d0 + i] = ksum[i];
    }
}

// KVt[bh][80][64]: rows 0-63 = KV[e][d], row 64 = Ksum[d], rows 65-79 = 0
__global__ __launch_bounds__(256)
void kv_finalize(const float* __restrict__ KVp, const float* __restrict__ Ksp,
                 ushort_t* __restrict__ KVt)
{
    const int bh = blockIdx.x, t = threadIdx.x;
    ushort_t* o = KVt + (size_t)bh * 5120;
#pragma unroll
    for (int i = 0; i < 16; i++) {
        const int idx = i * 256 + t;
        const int e = idx >> 6, d = idx & 63;
        float s = 0.f;
#pragma unroll
        for (int sp = 0; sp < 8; sp++)
            s += KVp[(((size_t)sp * 64 + bh) * 64 + d) * 64 + e];
        o[idx] = f2b(s);
    }
    if (t < 64) {
        float s = 0.f;
#pragma unroll
        for (int sp = 0; sp < 8; sp++) s += Ksp[((size_t)sp * 64 + bh) * 64 + t];
        o[4096 + t] = f2b(s);
    }
    for (int idx = 4160 + t; idx < 5120; idx += 256) o[idx] = 0;
}

// msg1[row][h*64+e] = (Qp[row] @ KV) * 1/(Qp[row].Ksum + eps)
__global__ __launch_bounds__(256, 2)
void attn_apply(const ushort_t* __restrict__ Qp, const ushort_t* __restrict__ KVt,
                ushort_t* __restrict__ msg1)
{
    __shared__ ushort_t As[256 * 64];
    __shared__ ushort_t Bs[80 * 64];
    const int t = threadIdx.x;
    const int ch = blockIdx.x, h = blockIdx.y, b = blockIdx.z;
    const int w = t >> 6, l = t & 63;
    const int lr = l & 15, lg = l >> 4;
    const int row0 = ch * 256;
    const int srow = t >> 3;
    const int sc = ((t & 7) ^ (srow & 7)) * 8;
    const ushort_t* kv = KVt + (size_t)(b * 8 + h) * 5120;
#pragma unroll
    for (int i = 0; i < 2; i++)
        gload16(kv + (size_t)(i * 32 + srow) * 64 + sc,
                (void*)(&Bs[i * 2048] + t * 8));
    if (t < 128)
        gload16(kv + (size_t)(64 + srow) * 64 + sc,
                (void*)(&Bs[4096] + t * 8));
    const ushort_t* qb = Qp + ((size_t)b * 8192 + row0) * 512 + h * 64;
#pragma unroll
    for (int i = 0; i < 8; i++)
        gload16(qb + (size_t)(i * 32 + srow) * 512 + sc,
                (void*)(&As[i * 2048] + t * 8));
    __syncthreads();
    f32x4 acc[4][5] = {};
    const int wr = w * 64;
#pragma unroll
    for (int ks = 0; ks < 2; ks++) {
        const int kswz = ((ks * 4 + lg) ^ (lr & 7)) * 8;
        short8 a[4], bb[5];
#pragma unroll
        for (int mf = 0; mf < 4; mf++)
            a[mf] = *(const short8*)&As[(wr + mf * 16 + lr) * 64 + kswz];
#pragma unroll
        for (int nf = 0; nf < 5; nf++)
            bb[nf] = *(const short8*)&Bs[(nf * 16 + lr) * 64 + kswz];
#pragma unroll
        for (int mf = 0; mf < 4; mf++)
#pragma unroll
            for (int nf = 0; nf < 5; nf++)
                acc[mf][nf] = __builtin_amdgcn_mfma_f32_16x16x32_bf16(
                    a[mf], bb[nf], acc[mf][nf], 0, 0, 0);
    }
#pragma unroll
    for (int mf = 0; mf < 4; mf++) {
#pragma unroll
        for (int i = 0; i < 4; i++) {
            const int m = row0 + wr + mf * 16 + lg * 4 + i;
            const float zden = __shfl(acc[mf][4][i], (l & 48));
            const float z = 1.f / (zden + 1e-6f);
#pragma unroll
            for (int nf = 0; nf < 4; nf++) {
                const int e = nf * 16 + lr;
                msg1[((size_t)b * 8192 + m) * 512 + h * 64 + e] =
                    f2b(acc[mf][nf][i] * z);
            }
        }
    }
}

// in-place LayerNorm over rows of 512 bf16; one wave per row (LN1)
__global__ __launch_bounds__(256)
void layer_norm_k(ushort_t* __restrict__ X, const float* __restrict__ g,
                  const float* __restrict__ bta)
{
    const int t = threadIdx.x;
    const int row = blockIdx.x * 4 + (t >> 6);
    const int l = t & 63;
    ushort_t* x = X + (size_t)row * 512;
    const short8 v = *(const short8*)&x[l * 8];
    float f[8];
    float s = 0.f;
#pragma unroll
    for (int j = 0; j < 8; j++) { f[j] = b2f((unsigned short)v[j]); s += f[j]; }
#pragma unroll
    for (int o = 32; o > 0; o >>= 1) s += __shfl_xor(s, o);
    const float mean = s * (1.f / 512.f);
    float vs = 0.f;
#pragma unroll
    for (int j = 0; j < 8; j++) { const float d = f[j] - mean; vs += d * d; }
#pragma unroll
    for (int o = 32; o > 0; o >>= 1) vs += __shfl_xor(vs, o);
    const float rstd = rsqrtf(vs * (1.f / 512.f) + 1e-5f);
    short8 ov;
#pragma unroll
    for (int j = 0; j < 8; j++) {
        const int c = l * 8 + j;
        ov[j] = (short)f2b((f[j] - mean) * rstd * g[c] + bta[c]);
    }
    *(short8*)&x[l * 8] = ov;
}

// Fused LN2 + residual + transpose
__global__ __launch_bounds__(256)
void ln2_final(const ushort_t* __restrict__ outp, const ushort_t* __restrict__ sfT,
               const float* __restrict__ g, const float* __restrict__ bta,
               float* __restrict__ out)
{
    __shared__ ushort_t tile[64][514];
    const int t = threadIdx.x;
    const int ns0 = blockIdx.x * 64, b = blockIdx.y;
    const int w = t >> 6, l = t & 63;
#pragma unroll
    for (int rr = 0; rr < 16; rr++) {
        const int r = w * 16 + rr;
        const size_t grow = (size_t)b * 8192 + ns0 + r;
        const short8 v = *(const short8*)&outp[grow * 512 + l * 8];
        float f[8];
        float s = 0.f;
#pragma unroll
        for (int j = 0; j < 8; j++) { f[j] = b2f((unsigned short)v[j]); s += f[j]; }
#pragma unroll
        for (int o = 32; o > 0; o >>= 1) s += __shfl_xor(s, o);
        const float mean = s * (1.f / 512.f);
        float vs = 0.f;
#pragma unroll
        for (int j = 0; j < 8; j++) { const float d = f[j] - mean; vs += d * d; }
#pragma unroll
        for (int o = 32; o > 0; o >>= 1) vs += __shfl_xor(vs, o);
        const float rstd = rsqrtf(vs * (1.f / 512.f) + 1e-5f);
        const short8 sv = *(const short8*)&sfT[grow * 512 + l * 8];
        short8 ov;
#pragma unroll
        for (int j = 0; j < 8; j++) {
            const int c = l * 8 + j;
            ov[j] = (short)f2b(b2f((unsigned short)sv[j]) +
                               (f[j] - mean) * rstd * g[c] + bta[c]);
        }
        *(short8*)&tile[r][l * 8] = ov;
    }
    __syncthreads();
#pragma unroll
    for (int i = 0; i < 32; i++) {
        const int d = (t >> 4) + i * 16;
        const int nss = (t & 15) * 4;
        float4 o;
        o.x = b2f(tile[nss + 0][d]);
        o.y = b2f(tile[nss + 1][d]);
        o.z = b2f(tile[nss + 2][d]);
        o.w = b2f(tile[nss + 3][d]);
        *(float4*)&out[((size_t)b * 512 + d) * 8192 + ns0 + nss] = o;
    }
}

// ---------------------------------------------------------------------------
extern "C" void kernel_launch(void* const* d_in, const int* in_sizes, int n_in,
                              void* d_out, int out_size, void* d_ws, size_t ws_size,
                              hipStream_t stream)
{
    (void)in_sizes; (void)n_in; (void)out_size; (void)ws_size;
    const float* search_feat   = (const float*)d_in[0];
    const float* template_feat = (const float*)d_in[2];
    const float* template_xyz  = (const float*)d_in[3];
    const float* pos_w1  = (const float*)d_in[4];
    const float* pos_b1  = (const float*)d_in[5];
    const float* pos_w2  = (const float*)d_in[6];
    const float* pos_b2  = (const float*)d_in[7];
    const float* wq      = (const float*)d_in[8];
    const float* wk      = (const float*)d_in[9];
    const float* wv      = (const float*)d_in[10];
    const float* w_merge = (const float*)d_in[11];
    const float* mlp_w1  = (const float*)d_in[12];
    const float* mlp_w2  = (const float*)d_in[13];
    const float* ln1_g   = (const float*)d_in[14];
    const float* ln1_b   = (const float*)d_in[15];
    const float* ln2_g   = (const float*)d_in[16];
    const float* ln2_b   = (const float*)d_in[17];
    float* out = (float*)d_out;

    char* ws = (char*)d_ws;
    ushort_t* sfT    = (ushort_t*)(ws + 0);           // [65536][512]
    ushort_t* Qp     = (ushort_t*)(ws + 67108864);    // [65536][512]; reused as outp
    ushort_t* tfT    = (ushort_t*)(ws + 134217728);   // [32768][512]
    ushort_t* msg2   = (ushort_t*)(ws + 134217728);   // overlaps tfT (dead by then)
    ushort_t* Kp     = (ushort_t*)(ws + 167772160);   // [32768][512]
    ushort_t* P1     = (ushort_t*)(ws + 201326592);   // [32768][512]
    ushort_t* Vv     = (ushort_t*)(ws + 234881024);   // [32768][512]
    ushort_t* msg1   = (ushort_t*)(ws + 268435456);   // [65536][512]
    ushort_t* hidden = (ushort_t*)(ws + 201326592);   // [65536][1024]
    ushort_t* outp   = Qp;
    ushort_t* wqT  = (ushort_t*)(ws + 335544320);
    ushort_t* wkT  = (ushort_t*)(ws + 336068608);
    ushort_t* wvT  = (ushort_t*)(ws + 336592896);
    ushort_t* wmT  = (ushort_t*)(ws + 337117184);
    ushort_t* wv2T = (ushort_t*)(ws + 337641472);     // (pw2@wv)^T  [512][512]
    ushort_t* w1T  = (ushort_t*)(ws + 338165760);
    ushort_t* w2T  = (ushort_t*)(ws + 340262912);
    ushort_t* pw2C = (ushort_t*)(ws + 341311488);     // bf16 cast of pw2
    float*    bv   = (float*)(ws + 342097920);        // b2@wv [512]
    float*    KVp  = (float*)(ws + 268435456);        // in msg1's dead region
    float*    Ksp  = (float*)(ws + 276824064);
    ushort_t* KVt  = (ushort_t*)(ws + 345571328);     // [64][80][64]

    prep<<<dim3(21186), 256, 0, stream>>>(
        search_feat, template_feat, template_xyz, pos_w1, pos_b1, pos_b2,
        wq, wk, wv, w_merge, pos_w2, mlp_w1, mlp_w2,
        sfT, tfT, P1, wqT, wkT, wvT, wmT, pw2C, w1T, w2T, bv);
    gemm_proj<<<dim3(3088), 256, 0, stream>>>(sfT, tfT, wvT, pw2C, wqT, wkT,
                                              Qp, Kp, wv2T);
    gemm128<4><<<dim3(1024), 256, 0, stream>>>(tfT, P1, wvT, wv2T, Vv, bv,
                                               512, 1024, 512, 512, 512,
                                               512, 512, 512, 4);
    kv_partial<<<dim3(8, 8, 8), 256, 0, stream>>>(Kp, Vv, KVp, Ksp);
    kv_finalize<<<dim3(64), 256, 0, stream>>>(KVp, Ksp, KVt);
    attn_apply<<<dim3(32, 8, 8), 256, 0, stream>>>(Qp, KVt, msg1);
    gemm128<0><<<dim3(2048), 256, 0, stream>>>(msg1, nullptr, wmT, wmT, msg2,
                                               nullptr, 512, 512, 512, 512, 0,
                                               512, 512, 512, 4);
    layer_norm_k<<<dim3(16384), 256, 0, stream>>>(msg2, ln1_g, ln1_b);
    gemm128<3><<<dim3(4096), 256, 0, stream>>>(sfT, msg2, w1T, w1T, hidden,
                                               nullptr, 1024, 1024, 512, 512, 512,
                                               1024, 1024, 1024, 8);
    gemm128<0><<<dim3(2048), 256, 0, stream>>>(hidden, nullptr, w2T, w2T, outp,
                                               nullptr, 512, 1024, 1024, 1024, 1024,
                                               1024, 1024, 1024, 4);
    ln2_final<<<dim3(128, 8), 256, 0, stream>>>(outp, sfT, ln2_g, ln2_b, out);
}